// Round 2
// baseline (1462.818 us; speedup 1.0000x reference)
//
#include <hip/hip_runtime.h>
#include <math.h>

#define HID 256
#define NBINS 4
#define NMIR 2000
#define NMRNA 20000
#define BB 16
#define NP 2048
#define PD 1024
#define EREG 300000
#define EPM 320000
#define EPI 32000

__device__ __forceinline__ float gelu_exact(float x) {
    return 0.5f * x * (1.0f + erff(x * 0.7071067811865475f));
}

// blockDim.x == 256 assumed
__device__ __forceinline__ float block_reduce_sum(float v, float* red) {
    int c = threadIdx.x;
    red[c] = v;
    __syncthreads();
    for (int st = 128; st > 0; st >>= 1) {
        if (c < st) red[c] += red[c + st];
        __syncthreads();
    }
    float r = red[0];
    __syncthreads();
    return r;
}

// ---------- transpose: in [R][C] -> out [C][R], R,C multiples of 32 ----------
__global__ void k_transpose(const float* __restrict__ in, float* __restrict__ out,
                            int R, int C) {
    __shared__ float tile[32][33];
    int c0 = blockIdx.x * 32, r0 = blockIdx.y * 32;
    int tx = threadIdx.x, ty = threadIdx.y;  // block (32,8)
    for (int k = 0; k < 32; k += 8)
        tile[ty + k][tx] = in[(size_t)(r0 + ty + k) * C + (c0 + tx)];
    __syncthreads();
    for (int k = 0; k < 32; k += 8)
        out[(size_t)(c0 + ty + k) * R + (r0 + tx)] = tile[tx][ty + k];
}

// ---------- edge scatter: out[dst[e]] += w[e] * emb[src[e]]  (one wave/edge) ----------
__global__ __launch_bounds__(256) void k_edge_scatter(
        const float* __restrict__ emb, const float* __restrict__ w,
        const int* __restrict__ src, const int* __restrict__ dst,
        float* __restrict__ out, int nedges) {
    int wave = (blockIdx.x * blockDim.x + threadIdx.x) >> 6;
    int lane = threadIdx.x & 63;
    int nwaves = (gridDim.x * blockDim.x) >> 6;
    for (int e = wave; e < nedges; e += nwaves) {
        int s = src[e], d = dst[e];
        float we = w[e];
        const float* hp = emb + (size_t)s * HID;
        float* op = out + (size_t)d * HID;
#pragma unroll
        for (int k = 0; k < 4; k++) {
            int col = lane + 64 * k;          // contiguous 256B per instruction
            atomicAdd(op + col, we * hp[col]);
        }
    }
}

// ---------- h_out = emb + gelu(agg @ W^T + b), wt is W^T laid out [i][c] ----------
template <int ROWS>
__global__ __launch_bounds__(256) void k_update_h(
        const float* __restrict__ agg, const float* __restrict__ emb,
        const float* __restrict__ wt, const float* __restrict__ bias,
        float* __restrict__ hout, int n) {
    int c = threadIdx.x;
    int row0 = blockIdx.x * ROWS;
    float acc[ROWS];
#pragma unroll
    for (int r = 0; r < ROWS; r++) acc[r] = 0.f;
    const float* aggp = agg + (size_t)row0 * HID;  // wave-uniform -> s_load
#pragma unroll 4
    for (int i = 0; i < HID; i++) {
        float wv = wt[(size_t)i * HID + c];  // coalesced, L2-resident
#pragma unroll
        for (int r = 0; r < ROWS; r++) acc[r] += aggp[r * HID + i] * wv;
    }
    float bv = bias[c];
#pragma unroll
    for (int r = 0; r < ROWS; r++) {
        int row = row0 + r;
        if (row < n) {
            size_t idx = (size_t)row * HID + c;
            hout[idx] = emb[idx] + gelu_exact(acc[r] + bv);
        }
    }
}

// ---------- patient readout: acc_pat[d] += w*h[src], both etypes, LDS-private ----------
__global__ __launch_bounds__(256) void k_pat_acc(
        const float* __restrict__ h_mrna, const float* __restrict__ h_mir,
        const float* __restrict__ w_mp, const int* __restrict__ src_mp,
        const int* __restrict__ dst_mp,
        const float* __restrict__ w_ip, const int* __restrict__ src_ip,
        const int* __restrict__ dst_ip,
        float* __restrict__ acc_pat) {
    __shared__ float lacc[BB * HID];  // 16 KB
    for (int i = threadIdx.x; i < BB * HID; i += 256) lacc[i] = 0.f;
    __syncthreads();
    int wave = (blockIdx.x * blockDim.x + threadIdx.x) >> 6;
    int lane = threadIdx.x & 63;
    int nwaves = (gridDim.x * blockDim.x) >> 6;
    for (int e = wave; e < EPM; e += nwaves) {
        int s = src_mp[e], d = dst_mp[e];
        float we = w_mp[e];
        const float* hp = h_mrna + (size_t)s * HID;
#pragma unroll
        for (int k = 0; k < 4; k++) {
            int col = lane + 64 * k;
            atomicAdd(&lacc[d * HID + col], we * hp[col]);
        }
    }
    for (int e = wave; e < EPI; e += nwaves) {
        int s = src_ip[e], d = dst_ip[e];
        float we = w_ip[e];
        const float* hp = h_mir + (size_t)s * HID;
#pragma unroll
        for (int k = 0; k < 4; k++) {
            int col = lane + 64 * k;
            atomicAdd(&lacc[d * HID + col], we * hp[col]);
        }
    }
    __syncthreads();
    for (int i = threadIdx.x; i < BB * HID; i += 256) {
        float v = lacc[i];
        if (v != 0.f) atomicAdd(&acc_pat[i], v);
    }
}

// ---------- masked patch pooling: pooled[b][:] += sum_p mask[b][p]*patches[b][p][:] ----------
#define PSLICES 32
#define PCHUNK (NP / PSLICES)
__global__ __launch_bounds__(256) void k_pool(
        const float* __restrict__ patches, const float* __restrict__ mask,
        float* __restrict__ pooled) {
    int b = blockIdx.y;
    int p0 = blockIdx.x * PCHUNK;
    int t = threadIdx.x;  // 256 threads x float4 = 1024 = PD
    float4 acc = {0.f, 0.f, 0.f, 0.f};
    for (int p = p0; p < p0 + PCHUNK; p++) {
        float m = mask[b * NP + p];  // uniform -> s_load
        float4 v = ((const float4*)(patches + ((size_t)b * NP + p) * PD))[t];
        acc.x += m * v.x; acc.y += m * v.y; acc.z += m * v.z; acc.w += m * v.w;
    }
    float* op = pooled + (size_t)b * PD + t * 4;
    atomicAdd(op + 0, acc.x);
    atomicAdd(op + 1, acc.y);
    atomicAdd(op + 2, acc.z);
    atomicAdd(op + 3, acc.w);
}

// ---------- pat head: proj+gelu+LN -> pat; omics logits -> d_out[64..] ----------
__global__ __launch_bounds__(256) void k_pat_head(
        const float* __restrict__ acc_pat,
        const float* __restrict__ wt_proj, const float* __restrict__ proj_b,
        const float* __restrict__ ln_g, const float* __restrict__ ln_b,
        const float* __restrict__ omics_w, const float* __restrict__ omics_b,
        float* __restrict__ pat_out, float* __restrict__ out_omics) {
    __shared__ float red[256];
    int b = blockIdx.x, c = threadIdx.x;
    const float* ap = acc_pat + (size_t)b * HID;  // uniform
    float t = 0.f;
#pragma unroll 4
    for (int i = 0; i < HID; i++) t += ap[i] * wt_proj[(size_t)i * HID + c];
    float g = gelu_exact(t + proj_b[c]);
    float mean = block_reduce_sum(g, red) * (1.0f / HID);
    float d = g - mean;
    float var = block_reduce_sum(d * d, red) * (1.0f / HID);
    float x = d * rsqrtf(var + 1e-5f) * ln_g[c] + ln_b[c];
    pat_out[(size_t)b * HID + c] = x;
    for (int o = 0; o < NBINS; o++) {
        float r = block_reduce_sum(x * omics_w[o * HID + c], red);
        if (c == 0) out_omics[b * NBINS + o] = r + omics_b[o];
    }
}

// ---------- wsi head: lin(pooled)/denom, gelu, mlp, gelu, LN -> wsi ----------
__global__ __launch_bounds__(256) void k_wsi_head(
        const float* __restrict__ pooled, const float* __restrict__ mask,
        const float* __restrict__ wt_wsi, const float* __restrict__ wsi_b,
        const float* __restrict__ wt_mlp, const float* __restrict__ mlp_b,
        const float* __restrict__ wln_g, const float* __restrict__ wln_b,
        float* __restrict__ wsi_out) {
    __shared__ float red[256];
    __shared__ float sm[HID];
    int b = blockIdx.x, c = threadIdx.x;
    float s = 0.f;
    for (int p = c; p < NP; p += 256) s += mask[b * NP + p];
    float summask = block_reduce_sum(s, red);
    float denom = fmaxf(summask, 1.0f);
    const float* pr = pooled + (size_t)b * PD;  // uniform
    float t = 0.f;
#pragma unroll 4
    for (int i = 0; i < PD; i++) t += pr[i] * wt_wsi[(size_t)i * HID + c];
    float po = (t + summask * wsi_b[c]) / denom;
    sm[c] = gelu_exact(po);
    __syncthreads();
    float t2 = 0.f;
#pragma unroll 4
    for (int i = 0; i < HID; i++) t2 += sm[i] * wt_mlp[(size_t)i * HID + c];
    float m = gelu_exact(t2 + mlp_b[c]);
    float mean = block_reduce_sum(m, red) * (1.0f / HID);
    float d = m - mean;
    float var = block_reduce_sum(d * d, red) * (1.0f / HID);
    wsi_out[(size_t)b * HID + c] = d * rsqrtf(var + 1e-5f) * wln_g[c] + wln_b[c];
}

// ---------- fusion: gelu(lin(cat)) @ fuse_w2^T + b2 -> d_out[0..64) ----------
__global__ __launch_bounds__(256) void k_fuse(
        const float* __restrict__ pat, const float* __restrict__ wsi,
        const float* __restrict__ wt_f1, const float* __restrict__ f1_b,
        const float* __restrict__ f2_w, const float* __restrict__ f2_b,
        float* __restrict__ out_fused) {
    __shared__ float red[256];
    __shared__ float cat[2 * HID];
    int b = blockIdx.x, c = threadIdx.x;
    cat[c] = pat[(size_t)b * HID + c];
    cat[HID + c] = wsi[(size_t)b * HID + c];
    __syncthreads();
    float t = 0.f;
#pragma unroll 4
    for (int i = 0; i < 2 * HID; i++) t += cat[i] * wt_f1[(size_t)i * HID + c];
    float h1 = gelu_exact(t + f1_b[c]);
    for (int o = 0; o < NBINS; o++) {
        float r = block_reduce_sum(h1 * f2_w[o * HID + c], red);
        if (c == 0) out_fused[b * NBINS + o] = r + f2_b[o];
    }
}

extern "C" void kernel_launch(void* const* d_in, const int* in_sizes, int n_in,
                              void* d_out, int out_size, void* d_ws, size_t ws_size,
                              hipStream_t stream) {
    const float* emb_mirna  = (const float*)d_in[0];
    const float* emb_mrna   = (const float*)d_in[1];
    const float* w_mir2mrna = (const float*)d_in[2];
    const float* w_mrna2mir = (const float*)d_in[3];
    const float* w_mrna2pat = (const float*)d_in[4];
    const float* w_mir2pat  = (const float*)d_in[5];
    const float* reg_w_mrna = (const float*)d_in[6];
    const float* reg_b_mrna = (const float*)d_in[7];
    const float* reg_w_mirna= (const float*)d_in[8];
    const float* reg_b_mirna= (const float*)d_in[9];
    const float* proj_w     = (const float*)d_in[10];
    const float* proj_b     = (const float*)d_in[11];
    const float* ln_g       = (const float*)d_in[12];
    const float* ln_b       = (const float*)d_in[13];
    const float* omics_w    = (const float*)d_in[14];
    const float* omics_b    = (const float*)d_in[15];
    const float* wsi_w      = (const float*)d_in[16];
    const float* wsi_b      = (const float*)d_in[17];
    const float* mlp_w      = (const float*)d_in[18];
    const float* mlp_b      = (const float*)d_in[19];
    const float* wln_g      = (const float*)d_in[20];
    const float* wln_b      = (const float*)d_in[21];
    const float* fuse_w1    = (const float*)d_in[22];
    const float* fuse_b1    = (const float*)d_in[23];
    const float* fuse_w2    = (const float*)d_in[24];
    const float* fuse_b2    = (const float*)d_in[25];
    const float* patches    = (const float*)d_in[26];
    const float* mask       = (const float*)d_in[27];
    const int* src_m2M = (const int*)d_in[28];
    const int* dst_m2M = (const int*)d_in[29];
    const int* src_M2m = (const int*)d_in[30];
    const int* dst_M2m = (const int*)d_in[31];
    const int* src_M2p = (const int*)d_in[32];
    const int* dst_M2p = (const int*)d_in[33];
    const int* src_m2p = (const int*)d_in[34];
    const int* dst_m2p = (const int*)d_in[35];

    float* ws = (float*)d_ws;
    // workspace layout (floats)
    size_t off = 0;
    float* agg_mrna = ws + off; off += (size_t)NMRNA * HID;   // zeroed
    float* agg_mir  = ws + off; off += (size_t)NMIR * HID;    // zeroed
    float* acc_pat  = ws + off; off += (size_t)BB * HID;      // zeroed
    float* pooled   = ws + off; off += (size_t)BB * PD;       // zeroed
    size_t zero_floats = off;
    float* h_mrna   = ws + off; off += (size_t)NMRNA * HID;
    float* h_mir    = ws + off; off += (size_t)NMIR * HID;
    float* pat      = ws + off; off += (size_t)BB * HID;
    float* wsi      = ws + off; off += (size_t)BB * HID;
    float* wt_reg_mrna  = ws + off; off += (size_t)HID * HID;
    float* wt_reg_mirna = ws + off; off += (size_t)HID * HID;
    float* wt_proj      = ws + off; off += (size_t)HID * HID;
    float* wt_wsi       = ws + off; off += (size_t)PD * HID;
    float* wt_mlp       = ws + off; off += (size_t)HID * HID;
    float* wt_f1        = ws + off; off += (size_t)(2 * HID) * HID;

    float* out_fused = (float*)d_out;            // [16,4]
    float* out_omics = (float*)d_out + BB * NBINS;  // [16,4]

    hipMemsetAsync(d_ws, 0, zero_floats * sizeof(float), stream);

    // transposes: W [out][in] -> Wt [in][out]
    {
        dim3 blk(32, 8);
        k_transpose<<<dim3(HID / 32, HID / 32), blk, 0, stream>>>(reg_w_mrna, wt_reg_mrna, HID, HID);
        k_transpose<<<dim3(HID / 32, HID / 32), blk, 0, stream>>>(reg_w_mirna, wt_reg_mirna, HID, HID);
        k_transpose<<<dim3(HID / 32, HID / 32), blk, 0, stream>>>(proj_w, wt_proj, HID, HID);
        k_transpose<<<dim3(PD / 32, HID / 32), blk, 0, stream>>>(wsi_w, wt_wsi, HID, PD);
        k_transpose<<<dim3(HID / 32, HID / 32), blk, 0, stream>>>(mlp_w, wt_mlp, HID, HID);
        // fuse_w1 is [HID][2*HID] -> needs 2*HID/32 blocks in x (was the Round-1 bug)
        k_transpose<<<dim3(2 * HID / 32, HID / 32), blk, 0, stream>>>(fuse_w1, wt_f1, HID, 2 * HID);
    }

    // reg encoder edge scatters (use ORIGINAL embeddings)
    k_edge_scatter<<<2048, 256, 0, stream>>>(emb_mirna, w_mir2mrna, src_m2M, dst_m2M, agg_mrna, EREG);
    k_edge_scatter<<<2048, 256, 0, stream>>>(emb_mrna, w_mrna2mir, src_M2m, dst_M2m, agg_mir, EREG);

    // node updates
    k_update_h<8><<<NMRNA / 8, 256, 0, stream>>>(agg_mrna, emb_mrna, wt_reg_mrna, reg_b_mrna, h_mrna, NMRNA);
    k_update_h<8><<<NMIR / 8, 256, 0, stream>>>(agg_mir, emb_mirna, wt_reg_mirna, reg_b_mirna, h_mir, NMIR);

    // patient readout
    k_pat_acc<<<512, 256, 0, stream>>>(h_mrna, h_mir, w_mrna2pat, src_M2p, dst_M2p,
                                       w_mir2pat, src_m2p, dst_m2p, acc_pat);

    // pat head + omics logits
    k_pat_head<<<BB, 256, 0, stream>>>(acc_pat, wt_proj, proj_b, ln_g, ln_b,
                                       omics_w, omics_b, pat, out_omics);

    // wsi: masked pooling then head
    k_pool<<<dim3(PSLICES, BB), 256, 0, stream>>>(patches, mask, pooled);
    k_wsi_head<<<BB, 256, 0, stream>>>(pooled, mask, wt_wsi, wsi_b, wt_mlp, mlp_b,
                                       wln_g, wln_b, wsi);

    // fusion head
    k_fuse<<<BB, 256, 0, stream>>>(pat, wsi, wt_f1, fuse_b1, fuse_w2, fuse_b2, out_fused);
}

// Round 3
// 949.765 us; speedup vs baseline: 1.5402x; 1.5402x over previous
//
#include <hip/hip_runtime.h>
#include <math.h>

#define HID 256
#define NBINS 4
#define NMIR 2000
#define NMRNA 20000
#define BB 16
#define NP 2048
#define PD 1024
#define EREG 300000
#define EPM 320000
#define EPI 32000

__device__ __forceinline__ float gelu_exact(float x) {
    return 0.5f * x * (1.0f + erff(x * 0.7071067811865475f));
}

// blockDim.x == 256 assumed
__device__ __forceinline__ float block_reduce_sum(float v, float* red) {
    int c = threadIdx.x;
    red[c] = v;
    __syncthreads();
    for (int st = 128; st > 0; st >>= 1) {
        if (c < st) red[c] += red[c + st];
        __syncthreads();
    }
    float r = red[0];
    __syncthreads();
    return r;
}

// ---------- transpose: in [R][C] -> out [C][R], R,C multiples of 32 ----------
__global__ void k_transpose(const float* __restrict__ in, float* __restrict__ out,
                            int R, int C) {
    __shared__ float tile[32][33];
    int c0 = blockIdx.x * 32, r0 = blockIdx.y * 32;
    int tx = threadIdx.x, ty = threadIdx.y;  // block (32,8)
    for (int k = 0; k < 32; k += 8)
        tile[ty + k][tx] = in[(size_t)(r0 + ty + k) * C + (c0 + tx)];
    __syncthreads();
    for (int k = 0; k < 32; k += 8)
        out[(size_t)(c0 + ty + k) * R + (r0 + tx)] = tile[tx][ty + k];
}

// ---------- CSR build: histogram ----------
__global__ void k_hist(const int* __restrict__ dst, int* __restrict__ cnt, int n) {
    int i = blockIdx.x * blockDim.x + threadIdx.x;
    if (i < n) atomicAdd(&cnt[dst[i]], 1);
}

// ---------- CSR build: one-block exclusive scan (n <= 1024*chunk) ----------
__global__ __launch_bounds__(1024) void k_scan(const int* __restrict__ cnt,
                                               int* __restrict__ rowptr,
                                               int* __restrict__ cursor, int n) {
    __shared__ int part[1024];
    int t = threadIdx.x;
    int chunk = (n + 1023) >> 10;
    int beg = t * chunk;
    int end = min(beg + chunk, n);
    int s = 0;
    for (int i = beg; i < end; i++) s += cnt[i];
    part[t] = s;
    __syncthreads();
    for (int st = 1; st < 1024; st <<= 1) {
        int v = (t >= st) ? part[t - st] : 0;
        __syncthreads();
        part[t] += v;
        __syncthreads();
    }
    int off = part[t] - s;  // exclusive prefix
    for (int i = beg; i < end; i++) {
        rowptr[i] = off;
        cursor[i] = off;
        off += cnt[i];
    }
    if (end == n) rowptr[n] = off;  // all qualifying threads write the total
}

// ---------- CSR build: placement ----------
__global__ void k_place(const int* __restrict__ dst, int* __restrict__ cursor,
                        int* __restrict__ eidx, int n) {
    int i = blockIdx.x * blockDim.x + threadIdx.x;
    if (i < n) {
        int p = atomicAdd(&cursor[dst[i]], 1);
        eidx[p] = i;
    }
}

// ---------- CSR gather: one block per dst node, 4 waves split edges, LDS combine ----------
__global__ __launch_bounds__(256) void k_gather(
        const float* __restrict__ emb, const float* __restrict__ w,
        const int* __restrict__ src, const int* __restrict__ rowptr,
        const int* __restrict__ eidx, float* __restrict__ agg) {
    __shared__ float lacc[4][HID];
    int n = blockIdx.x;
    int wv = threadIdx.x >> 6, lane = threadIdx.x & 63;
    int beg = rowptr[n], end = rowptr[n + 1];
    float a0 = 0.f, a1 = 0.f, a2 = 0.f, a3 = 0.f;
    for (int j = beg + wv; j < end; j += 4) {
        int e = eidx[j];
        int s = src[e];
        float we = w[e];
        const float* hp = emb + (size_t)s * HID;
        a0 += we * hp[lane];
        a1 += we * hp[lane + 64];
        a2 += we * hp[lane + 128];
        a3 += we * hp[lane + 192];
    }
    lacc[wv][lane] = a0;
    lacc[wv][lane + 64] = a1;
    lacc[wv][lane + 128] = a2;
    lacc[wv][lane + 192] = a3;
    __syncthreads();
    int c = threadIdx.x;
    agg[(size_t)n * HID + c] = lacc[0][c] + lacc[1][c] + lacc[2][c] + lacc[3][c];
}

// ---------- h_out = emb + gelu(agg @ W^T + b), wt is W^T laid out [i][c] ----------
template <int ROWS>
__global__ __launch_bounds__(256) void k_update_h(
        const float* __restrict__ agg, const float* __restrict__ emb,
        const float* __restrict__ wt, const float* __restrict__ bias,
        float* __restrict__ hout, int n) {
    int c = threadIdx.x;
    int row0 = blockIdx.x * ROWS;
    float acc[ROWS];
#pragma unroll
    for (int r = 0; r < ROWS; r++) acc[r] = 0.f;
    const float* aggp = agg + (size_t)row0 * HID;  // wave-uniform -> s_load
#pragma unroll 4
    for (int i = 0; i < HID; i++) {
        float wv = wt[(size_t)i * HID + c];  // coalesced, L2-resident
#pragma unroll
        for (int r = 0; r < ROWS; r++) acc[r] += aggp[r * HID + i] * wv;
    }
    float bv = bias[c];
#pragma unroll
    for (int r = 0; r < ROWS; r++) {
        int row = row0 + r;
        if (row < n) {
            size_t idx = (size_t)row * HID + c;
            hout[idx] = emb[idx] + gelu_exact(acc[r] + bv);
        }
    }
}

// ---------- pat readout as dense weights: Wp[dst][src] += w ----------
__global__ void k_wscatter(const int* __restrict__ src, const int* __restrict__ dst,
                           const float* __restrict__ w, float* __restrict__ Wp,
                           int n, int srcdim) {
    int i = blockIdx.x * blockDim.x + threadIdx.x;
    if (i < n) atomicAdd(&Wp[(size_t)dst[i] * srcdim + src[i]], w[i]);
}

// ---------- acc_pat[b][c] += sum_g Wp[b][g] * h[g][c]  (skinny dense matmul) ----------
#define GCH 256
__global__ __launch_bounds__(256) void k_pat_dense(
        const float* __restrict__ Wp, const float* __restrict__ h,
        float* __restrict__ acc_pat, int ngenes) {
    int c = threadIdx.x;
    int g0 = blockIdx.x * GCH;
    int gend = min(g0 + GCH, ngenes);
    float acc[BB];
#pragma unroll
    for (int b = 0; b < BB; b++) acc[b] = 0.f;
    for (int g = g0; g < gend; g++) {
        float hv = h[(size_t)g * HID + c];  // coalesced
#pragma unroll
        for (int b = 0; b < BB; b++) acc[b] += Wp[(size_t)b * ngenes + g] * hv;  // uniform -> s_load
    }
#pragma unroll
    for (int b = 0; b < BB; b++) atomicAdd(&acc_pat[b * HID + c], acc[b]);
}

// ---------- masked patch pooling ----------
#define PSLICES 32
#define PCHUNK (NP / PSLICES)
__global__ __launch_bounds__(256) void k_pool(
        const float* __restrict__ patches, const float* __restrict__ mask,
        float* __restrict__ pooled) {
    int b = blockIdx.y;
    int p0 = blockIdx.x * PCHUNK;
    int t = threadIdx.x;  // 256 threads x float4 = 1024 = PD
    float4 acc = {0.f, 0.f, 0.f, 0.f};
    for (int p = p0; p < p0 + PCHUNK; p++) {
        float m = mask[b * NP + p];  // uniform -> s_load
        float4 v = ((const float4*)(patches + ((size_t)b * NP + p) * PD))[t];
        acc.x += m * v.x; acc.y += m * v.y; acc.z += m * v.z; acc.w += m * v.w;
    }
    float* op = pooled + (size_t)b * PD + t * 4;
    atomicAdd(op + 0, acc.x);
    atomicAdd(op + 1, acc.y);
    atomicAdd(op + 2, acc.z);
    atomicAdd(op + 3, acc.w);
}

// ---------- pat head: proj+gelu+LN -> pat; omics logits ----------
__global__ __launch_bounds__(256) void k_pat_head(
        const float* __restrict__ acc_pat,
        const float* __restrict__ wt_proj, const float* __restrict__ proj_b,
        const float* __restrict__ ln_g, const float* __restrict__ ln_b,
        const float* __restrict__ omics_w, const float* __restrict__ omics_b,
        float* __restrict__ pat_out, float* __restrict__ out_omics) {
    __shared__ float red[256];
    int b = blockIdx.x, c = threadIdx.x;
    const float* ap = acc_pat + (size_t)b * HID;  // uniform
    float t = 0.f;
#pragma unroll 4
    for (int i = 0; i < HID; i++) t += ap[i] * wt_proj[(size_t)i * HID + c];
    float g = gelu_exact(t + proj_b[c]);
    float mean = block_reduce_sum(g, red) * (1.0f / HID);
    float d = g - mean;
    float var = block_reduce_sum(d * d, red) * (1.0f / HID);
    float x = d * rsqrtf(var + 1e-5f) * ln_g[c] + ln_b[c];
    pat_out[(size_t)b * HID + c] = x;
    for (int o = 0; o < NBINS; o++) {
        float r = block_reduce_sum(x * omics_w[o * HID + c], red);
        if (c == 0) out_omics[b * NBINS + o] = r + omics_b[o];
    }
}

// ---------- wsi head ----------
__global__ __launch_bounds__(256) void k_wsi_head(
        const float* __restrict__ pooled, const float* __restrict__ mask,
        const float* __restrict__ wt_wsi, const float* __restrict__ wsi_b,
        const float* __restrict__ wt_mlp, const float* __restrict__ mlp_b,
        const float* __restrict__ wln_g, const float* __restrict__ wln_b,
        float* __restrict__ wsi_out) {
    __shared__ float red[256];
    __shared__ float sm[HID];
    int b = blockIdx.x, c = threadIdx.x;
    float s = 0.f;
    for (int p = c; p < NP; p += 256) s += mask[b * NP + p];
    float summask = block_reduce_sum(s, red);
    float denom = fmaxf(summask, 1.0f);
    const float* pr = pooled + (size_t)b * PD;  // uniform
    float t = 0.f;
#pragma unroll 4
    for (int i = 0; i < PD; i++) t += pr[i] * wt_wsi[(size_t)i * HID + c];
    float po = (t + summask * wsi_b[c]) / denom;
    sm[c] = gelu_exact(po);
    __syncthreads();
    float t2 = 0.f;
#pragma unroll 4
    for (int i = 0; i < HID; i++) t2 += sm[i] * wt_mlp[(size_t)i * HID + c];
    float m = gelu_exact(t2 + mlp_b[c]);
    float mean = block_reduce_sum(m, red) * (1.0f / HID);
    float d = m - mean;
    float var = block_reduce_sum(d * d, red) * (1.0f / HID);
    wsi_out[(size_t)b * HID + c] = d * rsqrtf(var + 1e-5f) * wln_g[c] + wln_b[c];
}

// ---------- fusion ----------
__global__ __launch_bounds__(256) void k_fuse(
        const float* __restrict__ pat, const float* __restrict__ wsi,
        const float* __restrict__ wt_f1, const float* __restrict__ f1_b,
        const float* __restrict__ f2_w, const float* __restrict__ f2_b,
        float* __restrict__ out_fused) {
    __shared__ float red[256];
    __shared__ float cat[2 * HID];
    int b = blockIdx.x, c = threadIdx.x;
    cat[c] = pat[(size_t)b * HID + c];
    cat[HID + c] = wsi[(size_t)b * HID + c];
    __syncthreads();
    float t = 0.f;
#pragma unroll 4
    for (int i = 0; i < 2 * HID; i++) t += cat[i] * wt_f1[(size_t)i * HID + c];
    float h1 = gelu_exact(t + f1_b[c]);
    for (int o = 0; o < NBINS; o++) {
        float r = block_reduce_sum(h1 * f2_w[o * HID + c], red);
        if (c == 0) out_fused[b * NBINS + o] = r + f2_b[o];
    }
}

extern "C" void kernel_launch(void* const* d_in, const int* in_sizes, int n_in,
                              void* d_out, int out_size, void* d_ws, size_t ws_size,
                              hipStream_t stream) {
    const float* emb_mirna  = (const float*)d_in[0];
    const float* emb_mrna   = (const float*)d_in[1];
    const float* w_mir2mrna = (const float*)d_in[2];
    const float* w_mrna2mir = (const float*)d_in[3];
    const float* w_mrna2pat = (const float*)d_in[4];
    const float* w_mir2pat  = (const float*)d_in[5];
    const float* reg_w_mrna = (const float*)d_in[6];
    const float* reg_b_mrna = (const float*)d_in[7];
    const float* reg_w_mirna= (const float*)d_in[8];
    const float* reg_b_mirna= (const float*)d_in[9];
    const float* proj_w     = (const float*)d_in[10];
    const float* proj_b     = (const float*)d_in[11];
    const float* ln_g       = (const float*)d_in[12];
    const float* ln_b       = (const float*)d_in[13];
    const float* omics_w    = (const float*)d_in[14];
    const float* omics_b    = (const float*)d_in[15];
    const float* wsi_w      = (const float*)d_in[16];
    const float* wsi_b      = (const float*)d_in[17];
    const float* mlp_w      = (const float*)d_in[18];
    const float* mlp_b      = (const float*)d_in[19];
    const float* wln_g      = (const float*)d_in[20];
    const float* wln_b      = (const float*)d_in[21];
    const float* fuse_w1    = (const float*)d_in[22];
    const float* fuse_b1    = (const float*)d_in[23];
    const float* fuse_w2    = (const float*)d_in[24];
    const float* fuse_b2    = (const float*)d_in[25];
    const float* patches    = (const float*)d_in[26];
    const float* mask       = (const float*)d_in[27];
    const int* src_m2M = (const int*)d_in[28];
    const int* dst_m2M = (const int*)d_in[29];
    const int* src_M2m = (const int*)d_in[30];
    const int* dst_M2m = (const int*)d_in[31];
    const int* src_M2p = (const int*)d_in[32];
    const int* dst_M2p = (const int*)d_in[33];
    const int* src_m2p = (const int*)d_in[34];
    const int* dst_m2p = (const int*)d_in[35];

    float* ws = (float*)d_ws;
    // ---- zeroed region (floats + int counters) ----
    size_t off = 0;
    float* acc_pat  = ws + off; off += (size_t)BB * HID;
    float* pooled   = ws + off; off += (size_t)BB * PD;
    float* Wp_mrna  = ws + off; off += (size_t)BB * NMRNA;
    float* Wp_mir   = ws + off; off += (size_t)BB * NMIR;
    int* cnt_mrna   = (int*)(ws + off); off += NMRNA;
    int* cnt_mir    = (int*)(ws + off); off += NMIR;
    size_t zero_floats = off;
    // ---- non-zeroed region ----
    float* agg_mrna = ws + off; off += (size_t)NMRNA * HID;
    float* agg_mir  = ws + off; off += (size_t)NMIR * HID;
    float* h_mrna   = ws + off; off += (size_t)NMRNA * HID;
    float* h_mir    = ws + off; off += (size_t)NMIR * HID;
    float* pat      = ws + off; off += (size_t)BB * HID;
    float* wsi      = ws + off; off += (size_t)BB * HID;
    float* wt_reg_mrna  = ws + off; off += (size_t)HID * HID;
    float* wt_reg_mirna = ws + off; off += (size_t)HID * HID;
    float* wt_proj      = ws + off; off += (size_t)HID * HID;
    float* wt_wsi       = ws + off; off += (size_t)PD * HID;
    float* wt_mlp       = ws + off; off += (size_t)HID * HID;
    float* wt_f1        = ws + off; off += (size_t)(2 * HID) * HID;
    int* rowptr_mrna = (int*)(ws + off); off += NMRNA + 1;
    int* cursor_mrna = (int*)(ws + off); off += NMRNA;
    int* rowptr_mir  = (int*)(ws + off); off += NMIR + 1;
    int* cursor_mir  = (int*)(ws + off); off += NMIR;
    int* eidx_mrna   = (int*)(ws + off); off += EREG;
    int* eidx_mir    = (int*)(ws + off); off += EREG;

    float* out_fused = (float*)d_out;               // [16,4]
    float* out_omics = (float*)d_out + BB * NBINS;  // [16,4]

    hipMemsetAsync(d_ws, 0, zero_floats * sizeof(float), stream);

    // transposes: W [out][in] -> Wt [in][out]
    {
        dim3 blk(32, 8);
        k_transpose<<<dim3(HID / 32, HID / 32), blk, 0, stream>>>(reg_w_mrna, wt_reg_mrna, HID, HID);
        k_transpose<<<dim3(HID / 32, HID / 32), blk, 0, stream>>>(reg_w_mirna, wt_reg_mirna, HID, HID);
        k_transpose<<<dim3(HID / 32, HID / 32), blk, 0, stream>>>(proj_w, wt_proj, HID, HID);
        k_transpose<<<dim3(PD / 32, HID / 32), blk, 0, stream>>>(wsi_w, wt_wsi, HID, PD);
        k_transpose<<<dim3(HID / 32, HID / 32), blk, 0, stream>>>(mlp_w, wt_mlp, HID, HID);
        k_transpose<<<dim3(2 * HID / 32, HID / 32), blk, 0, stream>>>(fuse_w1, wt_f1, HID, 2 * HID);
    }

    // ---- CSR build for both reg etypes ----
    k_hist<<<(EREG + 255) / 256, 256, 0, stream>>>(dst_m2M, cnt_mrna, EREG);
    k_hist<<<(EREG + 255) / 256, 256, 0, stream>>>(dst_M2m, cnt_mir, EREG);
    k_scan<<<1, 1024, 0, stream>>>(cnt_mrna, rowptr_mrna, cursor_mrna, NMRNA);
    k_scan<<<1, 1024, 0, stream>>>(cnt_mir, rowptr_mir, cursor_mir, NMIR);
    k_place<<<(EREG + 255) / 256, 256, 0, stream>>>(dst_m2M, cursor_mrna, eidx_mrna, EREG);
    k_place<<<(EREG + 255) / 256, 256, 0, stream>>>(dst_M2m, cursor_mir, eidx_mir, EREG);

    // ---- reg encoder: CSR gather (no atomics) ----
    k_gather<<<NMRNA, 256, 0, stream>>>(emb_mirna, w_mir2mrna, src_m2M, rowptr_mrna, eidx_mrna, agg_mrna);
    k_gather<<<NMIR, 256, 0, stream>>>(emb_mrna, w_mrna2mir, src_M2m, rowptr_mir, eidx_mir, agg_mir);

    // node updates
    k_update_h<8><<<NMRNA / 8, 256, 0, stream>>>(agg_mrna, emb_mrna, wt_reg_mrna, reg_b_mrna, h_mrna, NMRNA);
    k_update_h<8><<<NMIR / 8, 256, 0, stream>>>(agg_mir, emb_mirna, wt_reg_mirna, reg_b_mirna, h_mir, NMIR);

    // ---- patient readout: dense weight matrices + skinny matmul ----
    k_wscatter<<<(EPM + 255) / 256, 256, 0, stream>>>(src_M2p, dst_M2p, w_mrna2pat, Wp_mrna, EPM, NMRNA);
    k_wscatter<<<(EPI + 255) / 256, 256, 0, stream>>>(src_m2p, dst_m2p, w_mir2pat, Wp_mir, EPI, NMIR);
    k_pat_dense<<<(NMRNA + GCH - 1) / GCH, 256, 0, stream>>>(Wp_mrna, h_mrna, acc_pat, NMRNA);
    k_pat_dense<<<(NMIR + GCH - 1) / GCH, 256, 0, stream>>>(Wp_mir, h_mir, acc_pat, NMIR);

    // pat head + omics logits
    k_pat_head<<<BB, 256, 0, stream>>>(acc_pat, wt_proj, proj_b, ln_g, ln_b,
                                       omics_w, omics_b, pat, out_omics);

    // wsi: masked pooling then head
    k_pool<<<dim3(PSLICES, BB), 256, 0, stream>>>(patches, mask, pooled);
    k_wsi_head<<<BB, 256, 0, stream>>>(pooled, mask, wt_wsi, wsi_b, wt_mlp, mlp_b,
                                       wln_g, wln_b, wsi);

    // fusion head
    k_fuse<<<BB, 256, 0, stream>>>(pat, wsi, wt_f1, fuse_b1, fuse_w2, fuse_b2, out_fused);
}

// Round 5
// 760.334 us; speedup vs baseline: 1.9239x; 1.2491x over previous
//
#include <hip/hip_runtime.h>
#include <math.h>

#define HID 256
#define NBINS 4
#define NMIR 2000
#define NMRNA 20000
#define BB 16
#define NP 2048
#define PD 1024
#define EREG 300000
#define EPM 320000
#define EPI 32000

__device__ __forceinline__ float gelu_exact(float x) {
    return 0.5f * x * (1.0f + erff(x * 0.7071067811865475f));
}

// blockDim.x == 256 assumed
__device__ __forceinline__ float block_reduce_sum(float v, float* red) {
    int c = threadIdx.x;
    red[c] = v;
    __syncthreads();
    for (int st = 128; st > 0; st >>= 1) {
        if (c < st) red[c] += red[c + st];
        __syncthreads();
    }
    float r = red[0];
    __syncthreads();
    return r;
}

// ---------- transpose: in [R][C] -> out [C][R], R,C multiples of 32 ----------
__global__ void k_transpose(const float* __restrict__ in, float* __restrict__ out,
                            int R, int C) {
    __shared__ float tile[32][33];
    int c0 = blockIdx.x * 32, r0 = blockIdx.y * 32;
    int tx = threadIdx.x, ty = threadIdx.y;  // block (32,8)
    for (int k = 0; k < 32; k += 8)
        tile[ty + k][tx] = in[(size_t)(r0 + ty + k) * C + (c0 + tx)];
    __syncthreads();
    for (int k = 0; k < 32; k += 8)
        out[(size_t)(c0 + ty + k) * R + (r0 + tx)] = tile[tx][ty + k];
}

// ---------- CSR build: histogram ----------
__global__ void k_hist(const int* __restrict__ dst, int* __restrict__ cnt, int n) {
    int i = blockIdx.x * blockDim.x + threadIdx.x;
    if (i < n) atomicAdd(&cnt[dst[i]], 1);
}

// ---------- CSR build: one-block exclusive scan ----------
__global__ __launch_bounds__(1024) void k_scan(const int* __restrict__ cnt,
                                               int* __restrict__ rowptr,
                                               int* __restrict__ cursor, int n) {
    __shared__ int part[1024];
    int t = threadIdx.x;
    int chunk = (n + 1023) >> 10;
    int beg = t * chunk;
    int end = min(beg + chunk, n);
    int s = 0;
    for (int i = beg; i < end; i++) s += cnt[i];
    part[t] = s;
    __syncthreads();
    for (int st = 1; st < 1024; st <<= 1) {
        int v = (t >= st) ? part[t - st] : 0;
        __syncthreads();
        part[t] += v;
        __syncthreads();
    }
    int off = part[t] - s;  // exclusive prefix
    for (int i = beg; i < end; i++) {
        rowptr[i] = off;
        cursor[i] = off;
        off += cnt[i];
    }
    if (end == n) rowptr[n] = off;
}

// ---------- CSR build: placement ----------
__global__ void k_place(const int* __restrict__ dst, int* __restrict__ cursor,
                        int* __restrict__ eidx, int n) {
    int i = blockIdx.x * blockDim.x + threadIdx.x;
    if (i < n) {
        int p = atomicAdd(&cursor[dst[i]], 1);
        eidx[p] = i;
    }
}

// ---------- CSR gather: one block per dst node, 4 waves split edges ----------
__global__ __launch_bounds__(256) void k_gather(
        const float* __restrict__ emb, const float* __restrict__ w,
        const int* __restrict__ src, const int* __restrict__ rowptr,
        const int* __restrict__ eidx, float* __restrict__ agg) {
    __shared__ float lacc[4][HID];
    int n = blockIdx.x;
    int wv = threadIdx.x >> 6, lane = threadIdx.x & 63;
    int beg = rowptr[n], end = rowptr[n + 1];
    float a0 = 0.f, a1 = 0.f, a2 = 0.f, a3 = 0.f;
    for (int j = beg + wv; j < end; j += 4) {
        int e = eidx[j];
        int s = src[e];
        float we = w[e];
        const float* hp = emb + (size_t)s * HID;
        a0 += we * hp[lane];
        a1 += we * hp[lane + 64];
        a2 += we * hp[lane + 128];
        a3 += we * hp[lane + 192];
    }
    lacc[wv][lane] = a0;
    lacc[wv][lane + 64] = a1;
    lacc[wv][lane + 128] = a2;
    lacc[wv][lane + 192] = a3;
    __syncthreads();
    int c = threadIdx.x;
    agg[(size_t)n * HID + c] = lacc[0][c] + lacc[1][c] + lacc[2][c] + lacc[3][c];
}

// ---------- h_out = emb + gelu(agg @ W^T + b), wt is W^T laid out [i][c] ----------
template <int ROWS>
__global__ __launch_bounds__(256) void k_update_h(
        const float* __restrict__ agg, const float* __restrict__ emb,
        const float* __restrict__ wt, const float* __restrict__ bias,
        float* __restrict__ hout, int n) {
    int c = threadIdx.x;
    int row0 = blockIdx.x * ROWS;
    float acc[ROWS];
#pragma unroll
    for (int r = 0; r < ROWS; r++) acc[r] = 0.f;
    const float* aggp = agg + (size_t)row0 * HID;  // wave-uniform -> s_load
#pragma unroll 4
    for (int i = 0; i < HID; i++) {
        float wv = wt[(size_t)i * HID + c];  // coalesced, L2-resident
#pragma unroll
        for (int r = 0; r < ROWS; r++) acc[r] += aggp[r * HID + i] * wv;
    }
    float bv = bias[c];
#pragma unroll
    for (int r = 0; r < ROWS; r++) {
        int row = row0 + r;
        if (row < n) {
            size_t idx = (size_t)row * HID + c;
            hout[idx] = emb[idx] + gelu_exact(acc[r] + bv);
        }
    }
}

// ---------- pat readout as dense weights: Wp[dst][src] += w ----------
__global__ void k_wscatter(const int* __restrict__ src, const int* __restrict__ dst,
                           const float* __restrict__ w, float* __restrict__ Wp,
                           int n, int srcdim) {
    int i = blockIdx.x * blockDim.x + threadIdx.x;
    if (i < n) atomicAdd(&Wp[(size_t)dst[i] * srcdim + src[i]], w[i]);
}

// ---------- acc_pat[b][c] += sum_g Wp[b][g] * h[g][c]  (skinny dense matmul) ----------
#define GCH 128
__global__ __launch_bounds__(256) void k_pat_dense(
        const float* __restrict__ Wp, const float* __restrict__ h,
        float* __restrict__ acc_pat, int ngenes) {
    int c = threadIdx.x;
    int g0 = blockIdx.x * GCH;
    int gend = min(g0 + GCH, ngenes);
    float acc[BB];
#pragma unroll
    for (int b = 0; b < BB; b++) acc[b] = 0.f;
    for (int g = g0; g < gend; g++) {
        float hv = h[(size_t)g * HID + c];  // coalesced
#pragma unroll
        for (int b = 0; b < BB; b++) acc[b] += Wp[(size_t)b * ngenes + g] * hv;  // uniform
    }
#pragma unroll
    for (int b = 0; b < BB; b++) atomicAdd(&acc_pat[b * HID + c], acc[b]);
}

// ---------- masked patch pooling (raw sums, no denom) ----------
#define PSLICES 32
#define PCHUNK (NP / PSLICES)
__global__ __launch_bounds__(256) void k_pool(
        const float* __restrict__ patches, const float* __restrict__ mask,
        float* __restrict__ pooled) {
    int b = blockIdx.y;
    int p0 = blockIdx.x * PCHUNK;
    int t = threadIdx.x;  // 256 threads x float4 = 1024 = PD
    float4 acc = {0.f, 0.f, 0.f, 0.f};
    for (int p = p0; p < p0 + PCHUNK; p++) {
        float m = mask[b * NP + p];  // uniform -> s_load
        float4 v = ((const float4*)(patches + ((size_t)b * NP + p) * PD))[t];
        acc.x += m * v.x; acc.y += m * v.y; acc.z += m * v.z; acc.w += m * v.w;
    }
    float* op = pooled + (size_t)b * PD + t * 4;
    atomicAdd(op + 0, acc.x);
    atomicAdd(op + 1, acc.y);
    atomicAdd(op + 2, acc.z);
    atomicAdd(op + 3, acc.w);
}

// ---------- mask sums -> scale (=1/denom), bscale (=summask/denom) ----------
__global__ __launch_bounds__(1024) void k_masksum(
        const float* __restrict__ mask, float* __restrict__ scale,
        float* __restrict__ bscale) {
    int b = threadIdx.x >> 6, lane = threadIdx.x & 63;  // 16 waves, one per b
    float s = 0.f;
    for (int p = lane; p < NP; p += 64) s += mask[b * NP + p];
#pragma unroll
    for (int off = 32; off > 0; off >>= 1) s += __shfl_down(s, off, 64);
    if (lane == 0) {
        float denom = fmaxf(s, 1.0f);
        scale[b] = 1.0f / denom;
        bscale[b] = s / denom;
    }
}

// ---------- wave-per-output linear: y[b][o] = dot(x[b], W[o]) * sc + bias[o] * bs ----------
// W is ORIGINAL row-major [O][K]. One 64-lane wave per (b,o). Grid = B*O/4 blocks.
template <bool GELU_X>
__global__ __launch_bounds__(256) void k_lin_wave(
        const float* __restrict__ x, int xstride,
        const float* __restrict__ W, const float* __restrict__ bias,
        float* __restrict__ y, int ystride, int O, int K,
        const float* __restrict__ scale, const float* __restrict__ bscale) {
    int gw = (blockIdx.x * 256 + threadIdx.x) >> 6;
    int lane = threadIdx.x & 63;
    int b = gw / O, o = gw - b * O;
    const float* xr = x + (size_t)b * xstride;
    const float* wr = W + (size_t)o * K;
    float s = 0.f;
    for (int k = lane * 4; k < K; k += 256) {
        float4 wv = *(const float4*)(wr + k);
        float4 xv = *(const float4*)(xr + k);
        float x0 = xv.x, x1 = xv.y, x2 = xv.z, x3 = xv.w;
        if (GELU_X) {
            x0 = gelu_exact(x0); x1 = gelu_exact(x1);
            x2 = gelu_exact(x2); x3 = gelu_exact(x3);
        }
        s += x0 * wv.x + x1 * wv.y + x2 * wv.z + x3 * wv.w;
    }
#pragma unroll
    for (int off = 32; off > 0; off >>= 1) s += __shfl_down(s, off, 64);
    if (lane == 0) {
        float sc = scale ? scale[b] : 1.0f;
        float bs = bscale ? bscale[b] : 1.0f;
        y[(size_t)b * ystride + o] = s * sc + bias[o] * bs;
    }
}

// ---------- layernorm (optional gelu on input): 16 blocks x 256 ----------
template <bool GELU_X>
__global__ __launch_bounds__(256) void k_ln(
        const float* __restrict__ x, int xstride,
        const float* __restrict__ g, const float* __restrict__ bta,
        float* __restrict__ y, int ystride) {
    __shared__ float red[256];
    int b = blockIdx.x, c = threadIdx.x;
    float v = x[(size_t)b * xstride + c];
    if (GELU_X) v = gelu_exact(v);
    float mean = block_reduce_sum(v, red) * (1.0f / HID);
    float d = v - mean;
    float var = block_reduce_sum(d * d, red) * (1.0f / HID);
    y[(size_t)b * ystride + c] = d * rsqrtf(var + 1e-5f) * g[c] + bta[c];
}

extern "C" void kernel_launch(void* const* d_in, const int* in_sizes, int n_in,
                              void* d_out, int out_size, void* d_ws, size_t ws_size,
                              hipStream_t stream) {
    const float* emb_mirna  = (const float*)d_in[0];
    const float* emb_mrna   = (const float*)d_in[1];
    const float* w_mir2mrna = (const float*)d_in[2];
    const float* w_mrna2mir = (const float*)d_in[3];
    const float* w_mrna2pat = (const float*)d_in[4];
    const float* w_mir2pat  = (const float*)d_in[5];
    const float* reg_w_mrna = (const float*)d_in[6];
    const float* reg_b_mrna = (const float*)d_in[7];
    const float* reg_w_mirna= (const float*)d_in[8];
    const float* reg_b_mirna= (const float*)d_in[9];
    const float* proj_w     = (const float*)d_in[10];
    const float* proj_b     = (const float*)d_in[11];
    const float* ln_g       = (const float*)d_in[12];
    const float* ln_b       = (const float*)d_in[13];
    const float* omics_w    = (const float*)d_in[14];
    const float* omics_b    = (const float*)d_in[15];
    const float* wsi_w      = (const float*)d_in[16];
    const float* wsi_b      = (const float*)d_in[17];
    const float* mlp_w      = (const float*)d_in[18];
    const float* mlp_b      = (const float*)d_in[19];
    const float* wln_g      = (const float*)d_in[20];
    const float* wln_b      = (const float*)d_in[21];
    const float* fuse_w1    = (const float*)d_in[22];
    const float* fuse_b1    = (const float*)d_in[23];
    const float* fuse_w2    = (const float*)d_in[24];
    const float* fuse_b2    = (const float*)d_in[25];
    const float* patches    = (const float*)d_in[26];
    const float* mask       = (const float*)d_in[27];
    const int* src_m2M = (const int*)d_in[28];
    const int* dst_m2M = (const int*)d_in[29];
    const int* src_M2m = (const int*)d_in[30];
    const int* dst_M2m = (const int*)d_in[31];
    const int* src_M2p = (const int*)d_in[32];
    const int* dst_M2p = (const int*)d_in[33];
    const int* src_m2p = (const int*)d_in[34];
    const int* dst_m2p = (const int*)d_in[35];

    float* ws = (float*)d_ws;
    // ---- zeroed region ----
    size_t off = 0;
    float* acc_pat  = ws + off; off += (size_t)BB * HID;
    float* pooled   = ws + off; off += (size_t)BB * PD;
    float* Wp_mrna  = ws + off; off += (size_t)BB * NMRNA;
    float* Wp_mir   = ws + off; off += (size_t)BB * NMIR;
    int* cnt_mrna   = (int*)(ws + off); off += NMRNA;
    int* cnt_mir    = (int*)(ws + off); off += NMIR;
    size_t zero_floats = off;
    // ---- non-zeroed region ----
    float* agg_mrna = ws + off; off += (size_t)NMRNA * HID;
    float* agg_mir  = ws + off; off += (size_t)NMIR * HID;
    float* h_mrna   = ws + off; off += (size_t)NMRNA * HID;
    float* h_mir    = ws + off; off += (size_t)NMIR * HID;
    float* wt_reg_mrna  = ws + off; off += (size_t)HID * HID;
    float* wt_reg_mirna = ws + off; off += (size_t)HID * HID;
    float* t_pat    = ws + off; off += (size_t)BB * HID;   // proj output (pre-gelu/LN)
    float* po       = ws + off; off += (size_t)BB * HID;   // wsi lin1 output
    float* t2       = ws + off; off += (size_t)BB * HID;   // mlp output
    float* f1out    = ws + off; off += (size_t)BB * HID;   // fuse lin1 output
    float* cat      = ws + off; off += (size_t)BB * 2 * HID;  // [pat | wsi]
    float* sc_wsi   = ws + off; off += BB;
    float* bs_wsi   = ws + off; off += BB;
    int* rowptr_mrna = (int*)(ws + off); off += NMRNA + 1;
    int* cursor_mrna = (int*)(ws + off); off += NMRNA;
    int* rowptr_mir  = (int*)(ws + off); off += NMIR + 1;
    int* cursor_mir  = (int*)(ws + off); off += NMIR;
    int* eidx_mrna   = (int*)(ws + off); off += EREG;
    int* eidx_mir    = (int*)(ws + off); off += EREG;

    float* out_fused = (float*)d_out;               // [16,4]
    float* out_omics = (float*)d_out + BB * NBINS;  // [16,4]

    hipMemsetAsync(d_ws, 0, zero_floats * sizeof(float), stream);

    // transposes only for the reg-update matmul weights
    {
        dim3 blk(32, 8);
        k_transpose<<<dim3(HID / 32, HID / 32), blk, 0, stream>>>(reg_w_mrna, wt_reg_mrna, HID, HID);
        k_transpose<<<dim3(HID / 32, HID / 32), blk, 0, stream>>>(reg_w_mirna, wt_reg_mirna, HID, HID);
    }

    // ---- CSR build for both reg etypes ----
    k_hist<<<(EREG + 255) / 256, 256, 0, stream>>>(dst_m2M, cnt_mrna, EREG);
    k_hist<<<(EREG + 255) / 256, 256, 0, stream>>>(dst_M2m, cnt_mir, EREG);
    k_scan<<<1, 1024, 0, stream>>>(cnt_mrna, rowptr_mrna, cursor_mrna, NMRNA);
    k_scan<<<1, 1024, 0, stream>>>(cnt_mir, rowptr_mir, cursor_mir, NMIR);
    k_place<<<(EREG + 255) / 256, 256, 0, stream>>>(dst_m2M, cursor_mrna, eidx_mrna, EREG);
    k_place<<<(EREG + 255) / 256, 256, 0, stream>>>(dst_M2m, cursor_mir, eidx_mir, EREG);

    // ---- reg encoder: CSR gather (no atomics) ----
    k_gather<<<NMRNA, 256, 0, stream>>>(emb_mirna, w_mir2mrna, src_m2M, rowptr_mrna, eidx_mrna, agg_mrna);
    k_gather<<<NMIR, 256, 0, stream>>>(emb_mrna, w_mrna2mir, src_M2m, rowptr_mir, eidx_mir, agg_mir);

    // node updates
    k_update_h<8><<<NMRNA / 8, 256, 0, stream>>>(agg_mrna, emb_mrna, wt_reg_mrna, reg_b_mrna, h_mrna, NMRNA);
    k_update_h<8><<<NMIR / 8, 256, 0, stream>>>(agg_mir, emb_mirna, wt_reg_mirna, reg_b_mirna, h_mir, NMIR);

    // ---- patient readout: dense weight matrices + skinny matmul ----
    k_wscatter<<<(EPM + 255) / 256, 256, 0, stream>>>(src_M2p, dst_M2p, w_mrna2pat, Wp_mrna, EPM, NMRNA);
    k_wscatter<<<(EPI + 255) / 256, 256, 0, stream>>>(src_m2p, dst_m2p, w_mir2pat, Wp_mir, EPI, NMIR);
    k_pat_dense<<<(NMRNA + GCH - 1) / GCH, 256, 0, stream>>>(Wp_mrna, h_mrna, acc_pat, NMRNA);
    k_pat_dense<<<(NMIR + GCH - 1) / GCH, 256, 0, stream>>>(Wp_mir, h_mir, acc_pat, NMIR);

    // ---- pat head: proj -> gelu+LN -> cat[:,0:256]; omics logits ----
    // one wave per (b,o): grid = B*O/4 blocks of 256 threads (4 waves)
    k_lin_wave<false><<<(BB * HID) / 4, 256, 0, stream>>>(
        acc_pat, HID, proj_w, proj_b, t_pat, HID, HID, HID, nullptr, nullptr);
    k_ln<true><<<BB, 256, 0, stream>>>(t_pat, HID, ln_g, ln_b, cat, 2 * HID);
    k_lin_wave<false><<<(BB * NBINS) / 4, 256, 0, stream>>>(
        cat, 2 * HID, omics_w, omics_b, out_omics, NBINS, NBINS, HID, nullptr, nullptr);

    // ---- wsi path ----
    k_pool<<<dim3(PSLICES, BB), 256, 0, stream>>>(patches, mask, pooled);
    k_masksum<<<1, 1024, 0, stream>>>(mask, sc_wsi, bs_wsi);
    // po = (pooled_raw @ wsi_w^T)/denom + (summask/denom)*wsi_b
    k_lin_wave<false><<<(BB * HID) / 4, 256, 0, stream>>>(
        pooled, PD, wsi_w, wsi_b, po, HID, HID, PD, sc_wsi, bs_wsi);
    // t2 = gelu(po) @ mlp_w^T + mlp_b
    k_lin_wave<true><<<(BB * HID) / 4, 256, 0, stream>>>(
        po, HID, mlp_w, mlp_b, t2, HID, HID, HID, nullptr, nullptr);
    // wsi = LN(gelu(t2)) -> cat[:,256:512]
    k_ln<true><<<BB, 256, 0, stream>>>(t2, HID, wln_g, wln_b, cat + HID, 2 * HID);

    // ---- fusion head ----
    k_lin_wave<false><<<(BB * HID) / 4, 256, 0, stream>>>(
        cat, 2 * HID, fuse_w1, fuse_b1, f1out, HID, HID, 2 * HID, nullptr, nullptr);
    k_lin_wave<true><<<(BB * NBINS) / 4, 256, 0, stream>>>(
        f1out, HID, fuse_w2, fuse_b2, out_fused, NBINS, NBINS, HID, nullptr, nullptr);
}

// Round 6
// 684.148 us; speedup vs baseline: 2.1382x; 1.1114x over previous
//
#include <hip/hip_runtime.h>
#include <math.h>

#define HID 256
#define NBINS 4
#define NMIR 2000
#define NMRNA 20000
#define BB 16
#define NP 2048
#define PD 1024
#define EREG 300000
#define EPM 320000
#define EPI 32000

typedef __attribute__((ext_vector_type(8))) short bf16x8;
typedef __attribute__((ext_vector_type(4))) float f32x4;

__device__ __forceinline__ float gelu_exact(float x) {
    return 0.5f * x * (1.0f + erff(x * 0.7071067811865475f));
}

// fp32 -> bf16 round-to-nearest-even (bits)
__device__ __forceinline__ unsigned short f2b(float f) {
    union { float f; unsigned int u; } v; v.f = f;
    unsigned int u = v.u + 0x7fffu + ((v.u >> 16) & 1u);
    return (unsigned short)(u >> 16);
}

// blockDim.x == 256 assumed
__device__ __forceinline__ float block_reduce_sum(float v, float* red) {
    int c = threadIdx.x;
    red[c] = v;
    __syncthreads();
    for (int st = 128; st > 0; st >>= 1) {
        if (c < st) red[c] += red[c + st];
        __syncthreads();
    }
    float r = red[0];
    __syncthreads();
    return r;
}

// ---------- elementwise fp32 -> bf16 ----------
__global__ void k_f2b(const float* __restrict__ in, unsigned short* __restrict__ out, int n) {
    int i = blockIdx.x * blockDim.x + threadIdx.x;
    if (i < n) out[i] = f2b(in[i]);
}

// ---------- CSR build: histogram ----------
__global__ void k_hist(const int* __restrict__ dst, int* __restrict__ cnt, int n) {
    int i = blockIdx.x * blockDim.x + threadIdx.x;
    if (i < n) atomicAdd(&cnt[dst[i]], 1);
}

// ---------- CSR build: one-block exclusive scan ----------
__global__ __launch_bounds__(1024) void k_scan(const int* __restrict__ cnt,
                                               int* __restrict__ rowptr,
                                               int* __restrict__ cursor, int n) {
    __shared__ int part[1024];
    int t = threadIdx.x;
    int chunk = (n + 1023) >> 10;
    int beg = t * chunk;
    int end = min(beg + chunk, n);
    int s = 0;
    for (int i = beg; i < end; i++) s += cnt[i];
    part[t] = s;
    __syncthreads();
    for (int st = 1; st < 1024; st <<= 1) {
        int v = (t >= st) ? part[t - st] : 0;
        __syncthreads();
        part[t] += v;
        __syncthreads();
    }
    int off = part[t] - s;  // exclusive prefix
    for (int i = beg; i < end; i++) {
        rowptr[i] = off;
        cursor[i] = off;
        off += cnt[i];
    }
    if (end == n) rowptr[n] = off;
}

// ---------- CSR build: placement ----------
__global__ void k_place(const int* __restrict__ dst, int* __restrict__ cursor,
                        int* __restrict__ eidx, int n) {
    int i = blockIdx.x * blockDim.x + threadIdx.x;
    if (i < n) {
        int p = atomicAdd(&cursor[dst[i]], 1);
        eidx[p] = i;
    }
}

// ---------- CSR gather: one block per dst node, 4 waves split edges; bf16 out ----------
__global__ __launch_bounds__(256) void k_gather(
        const float* __restrict__ emb, const float* __restrict__ w,
        const int* __restrict__ src, const int* __restrict__ rowptr,
        const int* __restrict__ eidx, unsigned short* __restrict__ agg) {
    __shared__ float lacc[4][HID];
    int n = blockIdx.x;
    int wv = threadIdx.x >> 6, lane = threadIdx.x & 63;
    int beg = rowptr[n], end = rowptr[n + 1];
    float a0 = 0.f, a1 = 0.f, a2 = 0.f, a3 = 0.f;
    for (int j = beg + wv; j < end; j += 4) {
        int e = eidx[j];
        int s = src[e];
        float we = w[e];
        const float* hp = emb + (size_t)s * HID;
        a0 += we * hp[lane];
        a1 += we * hp[lane + 64];
        a2 += we * hp[lane + 128];
        a3 += we * hp[lane + 192];
    }
    lacc[wv][lane] = a0;
    lacc[wv][lane + 64] = a1;
    lacc[wv][lane + 128] = a2;
    lacc[wv][lane + 192] = a3;
    __syncthreads();
    int c = threadIdx.x;
    agg[(size_t)n * HID + c] = f2b(lacc[0][c] + lacc[1][c] + lacc[2][c] + lacc[3][c]);
}

// ---------- MFMA node update: h = emb + gelu(A @ Wb^T + bias) ----------
// A: [n][256] bf16 row-major. Wb: [256][256] bf16, ORIGINAL [out][in] layout (= B^T,
// which is exactly what the B-fragment wants: lane holds row n=lane&15, k contiguous).
// Block = 16 rows x 256 cols; wave wv covers cols [wv*64, wv*64+64) as 4 16-col tiles.
__global__ __launch_bounds__(256) void k_update_mfma(
        const unsigned short* __restrict__ A, const float* __restrict__ emb,
        const unsigned short* __restrict__ Wb, const float* __restrict__ bias,
        float* __restrict__ hout) {
    int wv = threadIdx.x >> 6;
    int lane = threadIdx.x & 63;
    int row0 = blockIdx.x * 16;
    int m = lane & 15;   // A row offset / D col offset
    int q = lane >> 4;   // quad: k = q*8 + j
    // A fragments for the whole K=256 (8 chunks of 32)
    bf16x8 afrag[8];
    const unsigned short* arow = A + (size_t)(row0 + m) * HID + q * 8;
#pragma unroll
    for (int kk = 0; kk < 8; kk++)
        afrag[kk] = *(const bf16x8*)(arow + kk * 32);
    f32x4 acc[4];
#pragma unroll
    for (int t = 0; t < 4; t++) acc[t] = (f32x4){0.f, 0.f, 0.f, 0.f};
    int col_base = wv * 64;
#pragma unroll
    for (int t = 0; t < 4; t++) {
        const unsigned short* brow = Wb + (size_t)(col_base + t * 16 + m) * HID + q * 8;
#pragma unroll
        for (int kk = 0; kk < 8; kk++) {
            bf16x8 bfrag = *(const bf16x8*)(brow + kk * 32);
            acc[t] = __builtin_amdgcn_mfma_f32_16x16x32_bf16(afrag[kk], bfrag, acc[t], 0, 0, 0);
        }
    }
    // epilogue: D[row = q*4 + r][col = m]  (verified m89/m91 C/D mapping)
#pragma unroll
    for (int t = 0; t < 4; t++) {
        int col = col_base + t * 16 + m;
        float bv = bias[col];
#pragma unroll
        for (int r = 0; r < 4; r++) {
            int row = row0 + q * 4 + r;
            size_t idx = (size_t)row * HID + col;
            hout[idx] = emb[idx] + gelu_exact(acc[t][r] + bv);
        }
    }
}

// ---------- pat readout as dense weights: Wp[dst][src] += w ----------
__global__ void k_wscatter(const int* __restrict__ src, const int* __restrict__ dst,
                           const float* __restrict__ w, float* __restrict__ Wp,
                           int n, int srcdim) {
    int i = blockIdx.x * blockDim.x + threadIdx.x;
    if (i < n) atomicAdd(&Wp[(size_t)dst[i] * srcdim + src[i]], w[i]);
}

// ---------- acc_pat[b][c] += sum_g Wp[b][g] * h[g][c]  (skinny dense matmul) ----------
#define GCH 128
__global__ __launch_bounds__(256) void k_pat_dense(
        const float* __restrict__ Wp, const float* __restrict__ h,
        float* __restrict__ acc_pat, int ngenes) {
    int c = threadIdx.x;
    int g0 = blockIdx.x * GCH;
    int gend = min(g0 + GCH, ngenes);
    float acc[BB];
#pragma unroll
    for (int b = 0; b < BB; b++) acc[b] = 0.f;
    for (int g = g0; g < gend; g++) {
        float hv = h[(size_t)g * HID + c];  // coalesced
#pragma unroll
        for (int b = 0; b < BB; b++) acc[b] += Wp[(size_t)b * ngenes + g] * hv;  // uniform
    }
#pragma unroll
    for (int b = 0; b < BB; b++) atomicAdd(&acc_pat[b * HID + c], acc[b]);
}

// ---------- masked patch pooling (raw sums, no denom) ----------
#define PSLICES 32
#define PCHUNK (NP / PSLICES)
__global__ __launch_bounds__(256) void k_pool(
        const float* __restrict__ patches, const float* __restrict__ mask,
        float* __restrict__ pooled) {
    int b = blockIdx.y;
    int p0 = blockIdx.x * PCHUNK;
    int t = threadIdx.x;  // 256 threads x float4 = 1024 = PD
    float4 acc = {0.f, 0.f, 0.f, 0.f};
    for (int p = p0; p < p0 + PCHUNK; p++) {
        float m = mask[b * NP + p];  // uniform -> s_load
        float4 v = ((const float4*)(patches + ((size_t)b * NP + p) * PD))[t];
        acc.x += m * v.x; acc.y += m * v.y; acc.z += m * v.z; acc.w += m * v.w;
    }
    float* op = pooled + (size_t)b * PD + t * 4;
    atomicAdd(op + 0, acc.x);
    atomicAdd(op + 1, acc.y);
    atomicAdd(op + 2, acc.z);
    atomicAdd(op + 3, acc.w);
}

// ---------- mask sums -> scale (=1/denom), bscale (=summask/denom) ----------
__global__ __launch_bounds__(1024) void k_masksum(
        const float* __restrict__ mask, float* __restrict__ scale,
        float* __restrict__ bscale) {
    int b = threadIdx.x >> 6, lane = threadIdx.x & 63;  // 16 waves, one per b
    float s = 0.f;
    for (int p = lane; p < NP; p += 64) s += mask[b * NP + p];
#pragma unroll
    for (int off = 32; off > 0; off >>= 1) s += __shfl_down(s, off, 64);
    if (lane == 0) {
        float denom = fmaxf(s, 1.0f);
        scale[b] = 1.0f / denom;
        bscale[b] = s / denom;
    }
}

// ---------- wave-per-output linear: y[b][o] = dot(x[b], W[o]) * sc + bias[o] * bs ----------
// W is ORIGINAL row-major [O][K]. One 64-lane wave per (b,o). Grid = B*O/4 blocks.
template <bool GELU_X>
__global__ __launch_bounds__(256) void k_lin_wave(
        const float* __restrict__ x, int xstride,
        const float* __restrict__ W, const float* __restrict__ bias,
        float* __restrict__ y, int ystride, int O, int K,
        const float* __restrict__ scale, const float* __restrict__ bscale) {
    int gw = (blockIdx.x * 256 + threadIdx.x) >> 6;
    int lane = threadIdx.x & 63;
    int b = gw / O, o = gw - b * O;
    const float* xr = x + (size_t)b * xstride;
    const float* wr = W + (size_t)o * K;
    float s = 0.f;
    for (int k = lane * 4; k < K; k += 256) {
        float4 wv = *(const float4*)(wr + k);
        float4 xv = *(const float4*)(xr + k);
        float x0 = xv.x, x1 = xv.y, x2 = xv.z, x3 = xv.w;
        if (GELU_X) {
            x0 = gelu_exact(x0); x1 = gelu_exact(x1);
            x2 = gelu_exact(x2); x3 = gelu_exact(x3);
        }
        s += x0 * wv.x + x1 * wv.y + x2 * wv.z + x3 * wv.w;
    }
#pragma unroll
    for (int off = 32; off > 0; off >>= 1) s += __shfl_down(s, off, 64);
    if (lane == 0) {
        float sc = scale ? scale[b] : 1.0f;
        float bs = bscale ? bscale[b] : 1.0f;
        y[(size_t)b * ystride + o] = s * sc + bias[o] * bs;
    }
}

// ---------- layernorm (optional gelu on input): 16 blocks x 256 ----------
template <bool GELU_X>
__global__ __launch_bounds__(256) void k_ln(
        const float* __restrict__ x, int xstride,
        const float* __restrict__ g, const float* __restrict__ bta,
        float* __restrict__ y, int ystride) {
    __shared__ float red[256];
    int b = blockIdx.x, c = threadIdx.x;
    float v = x[(size_t)b * xstride + c];
    if (GELU_X) v = gelu_exact(v);
    float mean = block_reduce_sum(v, red) * (1.0f / HID);
    float d = v - mean;
    float var = block_reduce_sum(d * d, red) * (1.0f / HID);
    y[(size_t)b * ystride + c] = d * rsqrtf(var + 1e-5f) * g[c] + bta[c];
}

extern "C" void kernel_launch(void* const* d_in, const int* in_sizes, int n_in,
                              void* d_out, int out_size, void* d_ws, size_t ws_size,
                              hipStream_t stream) {
    const float* emb_mirna  = (const float*)d_in[0];
    const float* emb_mrna   = (const float*)d_in[1];
    const float* w_mir2mrna = (const float*)d_in[2];
    const float* w_mrna2mir = (const float*)d_in[3];
    const float* w_mrna2pat = (const float*)d_in[4];
    const float* w_mir2pat  = (const float*)d_in[5];
    const float* reg_w_mrna = (const float*)d_in[6];
    const float* reg_b_mrna = (const float*)d_in[7];
    const float* reg_w_mirna= (const float*)d_in[8];
    const float* reg_b_mirna= (const float*)d_in[9];
    const float* proj_w     = (const float*)d_in[10];
    const float* proj_b     = (const float*)d_in[11];
    const float* ln_g       = (const float*)d_in[12];
    const float* ln_b       = (const float*)d_in[13];
    const float* omics_w    = (const float*)d_in[14];
    const float* omics_b    = (const float*)d_in[15];
    const float* wsi_w      = (const float*)d_in[16];
    const float* wsi_b      = (const float*)d_in[17];
    const float* mlp_w      = (const float*)d_in[18];
    const float* mlp_b      = (const float*)d_in[19];
    const float* wln_g      = (const float*)d_in[20];
    const float* wln_b      = (const float*)d_in[21];
    const float* fuse_w1    = (const float*)d_in[22];
    const float* fuse_b1    = (const float*)d_in[23];
    const float* fuse_w2    = (const float*)d_in[24];
    const float* fuse_b2    = (const float*)d_in[25];
    const float* patches    = (const float*)d_in[26];
    const float* mask       = (const float*)d_in[27];
    const int* src_m2M = (const int*)d_in[28];
    const int* dst_m2M = (const int*)d_in[29];
    const int* src_M2m = (const int*)d_in[30];
    const int* dst_M2m = (const int*)d_in[31];
    const int* src_M2p = (const int*)d_in[32];
    const int* dst_M2p = (const int*)d_in[33];
    const int* src_m2p = (const int*)d_in[34];
    const int* dst_m2p = (const int*)d_in[35];

    float* ws = (float*)d_ws;
    // ---- zeroed region ----
    size_t off = 0;
    float* acc_pat  = ws + off; off += (size_t)BB * HID;
    float* pooled   = ws + off; off += (size_t)BB * PD;
    float* Wp_mrna  = ws + off; off += (size_t)BB * NMRNA;
    float* Wp_mir   = ws + off; off += (size_t)BB * NMIR;
    int* cnt_mrna   = (int*)(ws + off); off += NMRNA;
    int* cnt_mir    = (int*)(ws + off); off += NMIR;
    size_t zero_floats = off;
    // ---- non-zeroed region ----
    unsigned short* agg_mrna_bf = (unsigned short*)(ws + off); off += (size_t)NMRNA * HID / 2;
    unsigned short* agg_mir_bf  = (unsigned short*)(ws + off); off += (size_t)NMIR * HID / 2;
    unsigned short* wb_mrna     = (unsigned short*)(ws + off); off += (size_t)HID * HID / 2;
    unsigned short* wb_mirna    = (unsigned short*)(ws + off); off += (size_t)HID * HID / 2;
    float* h_mrna   = ws + off; off += (size_t)NMRNA * HID;
    float* h_mir    = ws + off; off += (size_t)NMIR * HID;
    float* t_pat    = ws + off; off += (size_t)BB * HID;   // proj output (pre-gelu/LN)
    float* po       = ws + off; off += (size_t)BB * HID;   // wsi lin1 output
    float* t2       = ws + off; off += (size_t)BB * HID;   // mlp output
    float* f1out    = ws + off; off += (size_t)BB * HID;   // fuse lin1 output
    float* cat      = ws + off; off += (size_t)BB * 2 * HID;  // [pat | wsi]
    float* sc_wsi   = ws + off; off += BB;
    float* bs_wsi   = ws + off; off += BB;
    int* rowptr_mrna = (int*)(ws + off); off += NMRNA + 1;
    int* cursor_mrna = (int*)(ws + off); off += NMRNA;
    int* rowptr_mir  = (int*)(ws + off); off += NMIR + 1;
    int* cursor_mir  = (int*)(ws + off); off += NMIR;
    int* eidx_mrna   = (int*)(ws + off); off += EREG;
    int* eidx_mir    = (int*)(ws + off); off += EREG;

    float* out_fused = (float*)d_out;               // [16,4]
    float* out_omics = (float*)d_out + BB * NBINS;  // [16,4]

    hipMemsetAsync(d_ws, 0, zero_floats * sizeof(float), stream);

    // reg-update weights -> bf16 (NO transpose: [out][in] is the MFMA B-fragment layout)
    k_f2b<<<(HID * HID + 255) / 256, 256, 0, stream>>>(reg_w_mrna, wb_mrna, HID * HID);
    k_f2b<<<(HID * HID + 255) / 256, 256, 0, stream>>>(reg_w_mirna, wb_mirna, HID * HID);

    // ---- CSR build for both reg etypes ----
    k_hist<<<(EREG + 255) / 256, 256, 0, stream>>>(dst_m2M, cnt_mrna, EREG);
    k_hist<<<(EREG + 255) / 256, 256, 0, stream>>>(dst_M2m, cnt_mir, EREG);
    k_scan<<<1, 1024, 0, stream>>>(cnt_mrna, rowptr_mrna, cursor_mrna, NMRNA);
    k_scan<<<1, 1024, 0, stream>>>(cnt_mir, rowptr_mir, cursor_mir, NMIR);
    k_place<<<(EREG + 255) / 256, 256, 0, stream>>>(dst_m2M, cursor_mrna, eidx_mrna, EREG);
    k_place<<<(EREG + 255) / 256, 256, 0, stream>>>(dst_M2m, cursor_mir, eidx_mir, EREG);

    // ---- reg encoder: CSR gather (no atomics), bf16 agg out ----
    k_gather<<<NMRNA, 256, 0, stream>>>(emb_mirna, w_mir2mrna, src_m2M, rowptr_mrna, eidx_mrna, agg_mrna_bf);
    k_gather<<<NMIR, 256, 0, stream>>>(emb_mrna, w_mrna2mir, src_M2m, rowptr_mir, eidx_mir, agg_mir_bf);

    // node updates via MFMA (16 rows per block)
    k_update_mfma<<<NMRNA / 16, 256, 0, stream>>>(agg_mrna_bf, emb_mrna, wb_mrna, reg_b_mrna, h_mrna);
    k_update_mfma<<<NMIR / 16, 256, 0, stream>>>(agg_mir_bf, emb_mirna, wb_mirna, reg_b_mirna, h_mir);

    // ---- patient readout: dense weight matrices + skinny matmul ----
    k_wscatter<<<(EPM + 255) / 256, 256, 0, stream>>>(src_M2p, dst_M2p, w_mrna2pat, Wp_mrna, EPM, NMRNA);
    k_wscatter<<<(EPI + 255) / 256, 256, 0, stream>>>(src_m2p, dst_m2p, w_mir2pat, Wp_mir, EPI, NMIR);
    k_pat_dense<<<(NMRNA + GCH - 1) / GCH, 256, 0, stream>>>(Wp_mrna, h_mrna, acc_pat, NMRNA);
    k_pat_dense<<<(NMIR + GCH - 1) / GCH, 256, 0, stream>>>(Wp_mir, h_mir, acc_pat, NMIR);

    // ---- pat head: proj -> gelu+LN -> cat[:,0:256]; omics logits ----
    k_lin_wave<false><<<(BB * HID) / 4, 256, 0, stream>>>(
        acc_pat, HID, proj_w, proj_b, t_pat, HID, HID, HID, nullptr, nullptr);
    k_ln<true><<<BB, 256, 0, stream>>>(t_pat, HID, ln_g, ln_b, cat, 2 * HID);
    k_lin_wave<false><<<(BB * NBINS) / 4, 256, 0, stream>>>(
        cat, 2 * HID, omics_w, omics_b, out_omics, NBINS, NBINS, HID, nullptr, nullptr);

    // ---- wsi path ----
    k_pool<<<dim3(PSLICES, BB), 256, 0, stream>>>(patches, mask, pooled);
    k_masksum<<<1, 1024, 0, stream>>>(mask, sc_wsi, bs_wsi);
    k_lin_wave<false><<<(BB * HID) / 4, 256, 0, stream>>>(
        pooled, PD, wsi_w, wsi_b, po, HID, HID, PD, sc_wsi, bs_wsi);
    k_lin_wave<true><<<(BB * HID) / 4, 256, 0, stream>>>(
        po, HID, mlp_w, mlp_b, t2, HID, HID, HID, nullptr, nullptr);
    k_ln<true><<<BB, 256, 0, stream>>>(t2, HID, wln_g, wln_b, cat + HID, 2 * HID);

    // ---- fusion head ----
    k_lin_wave<false><<<(BB * HID) / 4, 256, 0, stream>>>(
        cat, 2 * HID, fuse_w1, fuse_b1, f1out, HID, HID, 2 * HID, nullptr, nullptr);
    k_lin_wave<true><<<(BB * NBINS) / 4, 256, 0, stream>>>(
        f1out, HID, fuse_w2, fuse_b2, out_fused, NBINS, NBINS, HID, nullptr, nullptr);
}

// Round 7
// 649.068 us; speedup vs baseline: 2.2537x; 1.0540x over previous
//
#include <hip/hip_runtime.h>
#include <math.h>

#define HID 256
#define NBINS 4
#define NMIR 2000
#define NMRNA 20000
#define NG (NMRNA + NMIR)   // 22000 union gene space
#define BB 16
#define NP 2048
#define PD 1024
#define EREG 300000
#define EPM 320000
#define EPI 32000

typedef __attribute__((ext_vector_type(8))) short bf16x8;
typedef __attribute__((ext_vector_type(4))) float f32x4;

__device__ __forceinline__ float gelu_exact(float x) {
    return 0.5f * x * (1.0f + erff(x * 0.7071067811865475f));
}

// fp32 -> bf16 round-to-nearest-even (bits)
__device__ __forceinline__ unsigned short f2b(float f) {
    union { float f; unsigned int u; } v; v.f = f;
    unsigned int u = v.u + 0x7fffu + ((v.u >> 16) & 1u);
    return (unsigned short)(u >> 16);
}

// blockDim.x == 256 assumed
__device__ __forceinline__ float block_reduce_sum(float v, float* red) {
    int c = threadIdx.x;
    red[c] = v;
    __syncthreads();
    for (int st = 128; st > 0; st >>= 1) {
        if (c < st) red[c] += red[c + st];
        __syncthreads();
    }
    float r = red[0];
    __syncthreads();
    return r;
}

// ---------- both reg weights fp32 -> bf16, one launch ----------
__global__ void k_f2b_w(const float* __restrict__ wA, const float* __restrict__ wB,
                        unsigned short* __restrict__ out) {
    int i = blockIdx.x * blockDim.x + threadIdx.x;
    if (i < HID * HID) out[i] = f2b(wA[i]);
    else if (i < 2 * HID * HID) out[i] = f2b(wB[i - HID * HID]);
}

// ---------- CSR histogram, both etypes into contiguous cnt[NG] ----------
__global__ void k_hist2(const int* __restrict__ dA, const int* __restrict__ dB,
                        int* __restrict__ cnt) {
    int i = blockIdx.x * blockDim.x + threadIdx.x;
    if (i < EREG) atomicAdd(&cnt[dA[i]], 1);
    else if (i < 2 * EREG) atomicAdd(&cnt[NMRNA + dB[i - EREG]], 1);
}

// ---------- exclusive scan: block 0 -> mrna CSR, block 1 -> mir CSR ----------
__global__ __launch_bounds__(1024) void k_scan2(const int* __restrict__ cnt,
                                                int* __restrict__ rpA, int* __restrict__ cuA,
                                                int* __restrict__ rpB, int* __restrict__ cuB) {
    __shared__ int part[1024];
    const int* c = (blockIdx.x == 0) ? cnt : cnt + NMRNA;
    int n = (blockIdx.x == 0) ? NMRNA : NMIR;
    int* rowptr = (blockIdx.x == 0) ? rpA : rpB;
    int* cursor = (blockIdx.x == 0) ? cuA : cuB;
    int t = threadIdx.x;
    int chunk = (n + 1023) >> 10;
    int beg = t * chunk;
    int end = min(beg + chunk, n);
    int s = 0;
    for (int i = beg; i < end; i++) s += c[i];
    part[t] = s;
    __syncthreads();
    for (int st = 1; st < 1024; st <<= 1) {
        int v = (t >= st) ? part[t - st] : 0;
        __syncthreads();
        part[t] += v;
        __syncthreads();
    }
    int off = part[t] - s;  // exclusive prefix
    for (int i = beg; i < end; i++) {
        rowptr[i] = off;
        cursor[i] = off;
        off += c[i];
    }
    if (end == n) rowptr[n] = off;
}

// ---------- placement: permute (src, w) into CSR order (no eidx indirection) ----------
__global__ void k_place2(
        const int* __restrict__ srcA, const int* __restrict__ dstA, const float* __restrict__ wA,
        int* __restrict__ cuA, int* __restrict__ srcpA, float* __restrict__ wpA,
        const int* __restrict__ srcB, const int* __restrict__ dstB, const float* __restrict__ wB,
        int* __restrict__ cuB, int* __restrict__ srcpB, float* __restrict__ wpB) {
    int i = blockIdx.x * blockDim.x + threadIdx.x;
    if (i < EREG) {
        int p = atomicAdd(&cuA[dstA[i]], 1);
        srcpA[p] = srcA[i];
        wpA[p] = wA[i];
    } else if (i < 2 * EREG) {
        int j = i - EREG;
        int p = atomicAdd(&cuB[dstB[j]], 1);
        srcpB[p] = srcB[j];
        wpB[p] = wB[j];
    }
}

// ---------- CSR gather, both etypes: one block per dst node; bf16 out [NG][256] ----------
__global__ __launch_bounds__(256) void k_gather2(
        const float* __restrict__ emb_mirna, const float* __restrict__ emb_mrna,
        const int* __restrict__ rpA, const int* __restrict__ srcpA, const float* __restrict__ wpA,
        const int* __restrict__ rpB, const int* __restrict__ srcpB, const float* __restrict__ wpB,
        unsigned short* __restrict__ agg) {
    __shared__ float lacc[4][HID];
    int n = blockIdx.x;
    const float* emb;
    const int* rp; const int* srcp; const float* wp;
    int node;
    if (n < NMRNA) { emb = emb_mirna; rp = rpA; srcp = srcpA; wp = wpA; node = n; }
    else           { emb = emb_mrna;  rp = rpB; srcp = srcpB; wp = wpB; node = n - NMRNA; }
    int wv = threadIdx.x >> 6, lane = threadIdx.x & 63;
    int beg = rp[node], end = rp[node + 1];
    float a0 = 0.f, a1 = 0.f, a2 = 0.f, a3 = 0.f;
    for (int j = beg + wv; j < end; j += 4) {
        int s = srcp[j];          // wave-uniform -> s_load
        float we = wp[j];
        const float* hp = emb + (size_t)s * HID;
        a0 += we * hp[lane];
        a1 += we * hp[lane + 64];
        a2 += we * hp[lane + 128];
        a3 += we * hp[lane + 192];
    }
    lacc[wv][lane] = a0;
    lacc[wv][lane + 64] = a1;
    lacc[wv][lane + 128] = a2;
    lacc[wv][lane + 192] = a3;
    __syncthreads();
    int c = threadIdx.x;
    agg[(size_t)n * HID + c] = f2b(lacc[0][c] + lacc[1][c] + lacc[2][c] + lacc[3][c]);
}

// ---------- MFMA node update, both etypes: h = emb + gelu(A @ W^T + bias) ----------
// A: [NG][256] bf16. wb: [2][256][256] bf16 in ORIGINAL [out][in] layout (B-fragment-ready).
// Block = 16 rows x 256 cols; wave wv covers cols [wv*64, wv*64+64) as 4 16-col tiles.
__global__ __launch_bounds__(256) void k_update2(
        const unsigned short* __restrict__ A,
        const float* __restrict__ emb_mrna, const float* __restrict__ emb_mirna,
        const unsigned short* __restrict__ wb,
        const float* __restrict__ bias_mrna, const float* __restrict__ bias_mirna,
        float* __restrict__ h) {
    int row0 = blockIdx.x * 16;   // global row (NG space); NMRNA % 16 == 0, never straddles
    const float* emb; const unsigned short* Wb; const float* bias; int base;
    if (row0 < NMRNA) { emb = emb_mrna;  Wb = wb;             bias = bias_mrna;  base = 0; }
    else              { emb = emb_mirna; Wb = wb + HID * HID; bias = bias_mirna; base = NMRNA; }
    int wv = threadIdx.x >> 6;
    int lane = threadIdx.x & 63;
    int m = lane & 15;   // A row offset / D col offset
    int q = lane >> 4;   // quad: k = q*8 + j
    bf16x8 afrag[8];
    const unsigned short* arow = A + (size_t)(row0 + m) * HID + q * 8;
#pragma unroll
    for (int kk = 0; kk < 8; kk++)
        afrag[kk] = *(const bf16x8*)(arow + kk * 32);
    f32x4 acc[4];
#pragma unroll
    for (int t = 0; t < 4; t++) acc[t] = (f32x4){0.f, 0.f, 0.f, 0.f};
    int col_base = wv * 64;
#pragma unroll
    for (int t = 0; t < 4; t++) {
        const unsigned short* brow = Wb + (size_t)(col_base + t * 16 + m) * HID + q * 8;
#pragma unroll
        for (int kk = 0; kk < 8; kk++) {
            bf16x8 bfrag = *(const bf16x8*)(brow + kk * 32);
            acc[t] = __builtin_amdgcn_mfma_f32_16x16x32_bf16(afrag[kk], bfrag, acc[t], 0, 0, 0);
        }
    }
#pragma unroll
    for (int t = 0; t < 4; t++) {
        int col = col_base + t * 16 + m;
        float bv = bias[col];
#pragma unroll
        for (int r = 0; r < 4; r++) {
            int row = row0 + q * 4 + r;                      // global
            size_t idxh = (size_t)row * HID + col;
            size_t idxe = (size_t)(row - base) * HID + col;  // local emb row
            h[idxh] = emb[idxe] + gelu_exact(acc[t][r] + bv);
        }
    }
}

// ---------- pat readout weights, both etypes: Wp[b][g] += w (g in NG union space) ----------
__global__ void k_wscatter2(
        const int* __restrict__ srcA, const int* __restrict__ dstA, const float* __restrict__ wA,
        const int* __restrict__ srcB, const int* __restrict__ dstB, const float* __restrict__ wB,
        float* __restrict__ Wp) {
    int i = blockIdx.x * blockDim.x + threadIdx.x;
    if (i < EPM) {
        atomicAdd(&Wp[(size_t)dstA[i] * NG + srcA[i]], wA[i]);
    } else if (i < EPM + EPI) {
        int j = i - EPM;
        atomicAdd(&Wp[(size_t)dstB[j] * NG + NMRNA + srcB[j]], wB[j]);
    }
}

// ---------- acc_pat[b][c] += sum_g Wp[b][g] * h[g][c]  (skinny dense matmul) ----------
#define GCH 128
__global__ __launch_bounds__(256) void k_pat_dense(
        const float* __restrict__ Wp, const float* __restrict__ h,
        float* __restrict__ acc_pat) {
    int c = threadIdx.x;
    int g0 = blockIdx.x * GCH;
    int gend = min(g0 + GCH, NG);
    float acc[BB];
#pragma unroll
    for (int b = 0; b < BB; b++) acc[b] = 0.f;
    for (int g = g0; g < gend; g++) {
        float hv = h[(size_t)g * HID + c];  // coalesced
#pragma unroll
        for (int b = 0; b < BB; b++) acc[b] += Wp[(size_t)b * NG + g] * hv;  // uniform
    }
#pragma unroll
    for (int b = 0; b < BB; b++) atomicAdd(&acc_pat[b * HID + c], acc[b]);
}

// ---------- masked patch pooling (raw sums, no denom) ----------
#define PSLICES 32
#define PCHUNK (NP / PSLICES)
__global__ __launch_bounds__(256) void k_pool(
        const float* __restrict__ patches, const float* __restrict__ mask,
        float* __restrict__ pooled) {
    int b = blockIdx.y;
    int p0 = blockIdx.x * PCHUNK;
    int t = threadIdx.x;  // 256 threads x float4 = 1024 = PD
    float4 acc = {0.f, 0.f, 0.f, 0.f};
    for (int p = p0; p < p0 + PCHUNK; p++) {
        float m = mask[b * NP + p];  // uniform -> s_load
        float4 v = ((const float4*)(patches + ((size_t)b * NP + p) * PD))[t];
        acc.x += m * v.x; acc.y += m * v.y; acc.z += m * v.z; acc.w += m * v.w;
    }
    float* op = pooled + (size_t)b * PD + t * 4;
    atomicAdd(op + 0, acc.x);
    atomicAdd(op + 1, acc.y);
    atomicAdd(op + 2, acc.z);
    atomicAdd(op + 3, acc.w);
}

// ---------- fused heads: one block per patient b runs the whole head chain ----------
__global__ __launch_bounds__(256) void k_head(
        const float* __restrict__ pooled, const float* __restrict__ mask,
        const float* __restrict__ acc_pat,
        const float* __restrict__ proj_w, const float* __restrict__ proj_b,
        const float* __restrict__ ln_g, const float* __restrict__ ln_b,
        const float* __restrict__ omics_w, const float* __restrict__ omics_b,
        const float* __restrict__ wsi_w, const float* __restrict__ wsi_b,
        const float* __restrict__ mlp_w, const float* __restrict__ mlp_b,
        const float* __restrict__ wln_g, const float* __restrict__ wln_b,
        const float* __restrict__ fuse_w1, const float* __restrict__ fuse_b1,
        const float* __restrict__ fuse_w2, const float* __restrict__ fuse_b2,
        float* __restrict__ out_fused, float* __restrict__ out_omics) {
    __shared__ float red[256];
    __shared__ float vec[2 * HID];   // cat = [pat | wsi]
    __shared__ float tmp[HID];
    int b = blockIdx.x, c = threadIdx.x;

    // ---- pat path: proj -> gelu -> LN -> vec[0:256); omics logits ----
    const float* ap = acc_pat + (size_t)b * HID;
    float t = 0.f;
    for (int i = 0; i < HID; i += 4) {
        float4 w4 = *(const float4*)(proj_w + (size_t)c * HID + i);
        float4 x4 = *(const float4*)(ap + i);
        t += x4.x * w4.x + x4.y * w4.y + x4.z * w4.z + x4.w * w4.w;
    }
    float g = gelu_exact(t + proj_b[c]);
    float mean = block_reduce_sum(g, red) * (1.0f / HID);
    float d = g - mean;
    float var = block_reduce_sum(d * d, red) * (1.0f / HID);
    float patv = d * rsqrtf(var + 1e-5f) * ln_g[c] + ln_b[c];
    vec[c] = patv;
    for (int o = 0; o < NBINS; o++) {
        float r = block_reduce_sum(patv * omics_w[o * HID + c], red);
        if (c == 0) out_omics[b * NBINS + o] = r + omics_b[o];
    }

    // ---- wsi path: masksum, lin1/denom, gelu, mlp, gelu, LN -> vec[256:512) ----
    float s = 0.f;
    for (int p = c; p < NP; p += 256) s += mask[b * NP + p];
    float summask = block_reduce_sum(s, red);
    float denom = fmaxf(summask, 1.0f);
    const float* pr = pooled + (size_t)b * PD;
    float t1 = 0.f;
    for (int i = 0; i < PD; i += 4) {
        float4 w4 = *(const float4*)(wsi_w + (size_t)c * PD + i);
        float4 x4 = *(const float4*)(pr + i);
        t1 += x4.x * w4.x + x4.y * w4.y + x4.z * w4.z + x4.w * w4.w;
    }
    float po = t1 / denom + wsi_b[c] * (summask / denom);
    tmp[c] = gelu_exact(po);
    __syncthreads();
    float t2 = 0.f;
    for (int i = 0; i < HID; i += 4) {
        float4 w4 = *(const float4*)(mlp_w + (size_t)c * HID + i);
        float4 x4 = *(const float4*)(tmp + i);
        t2 += x4.x * w4.x + x4.y * w4.y + x4.z * w4.z + x4.w * w4.w;
    }
    float m = gelu_exact(t2 + mlp_b[c]);
    mean = block_reduce_sum(m, red) * (1.0f / HID);
    d = m - mean;
    var = block_reduce_sum(d * d, red) * (1.0f / HID);
    vec[HID + c] = d * rsqrtf(var + 1e-5f) * wln_g[c] + wln_b[c];
    __syncthreads();

    // ---- fusion: gelu(cat @ fuse_w1^T + b1) @ fuse_w2^T + b2 ----
    float t3 = 0.f;
    for (int i = 0; i < 2 * HID; i += 4) {
        float4 w4 = *(const float4*)(fuse_w1 + (size_t)c * (2 * HID) + i);
        float4 x4 = *(const float4*)(vec + i);
        t3 += x4.x * w4.x + x4.y * w4.y + x4.z * w4.z + x4.w * w4.w;
    }
    float h1 = gelu_exact(t3 + fuse_b1[c]);
    for (int o = 0; o < NBINS; o++) {
        float r = block_reduce_sum(h1 * fuse_w2[o * HID + c], red);
        if (c == 0) out_fused[b * NBINS + o] = r + fuse_b2[o];
    }
}

extern "C" void kernel_launch(void* const* d_in, const int* in_sizes, int n_in,
                              void* d_out, int out_size, void* d_ws, size_t ws_size,
                              hipStream_t stream) {
    const float* emb_mirna  = (const float*)d_in[0];
    const float* emb_mrna   = (const float*)d_in[1];
    const float* w_mir2mrna = (const float*)d_in[2];
    const float* w_mrna2mir = (const float*)d_in[3];
    const float* w_mrna2pat = (const float*)d_in[4];
    const float* w_mir2pat  = (const float*)d_in[5];
    const float* reg_w_mrna = (const float*)d_in[6];
    const float* reg_b_mrna = (const float*)d_in[7];
    const float* reg_w_mirna= (const float*)d_in[8];
    const float* reg_b_mirna= (const float*)d_in[9];
    const float* proj_w     = (const float*)d_in[10];
    const float* proj_b     = (const float*)d_in[11];
    const float* ln_g       = (const float*)d_in[12];
    const float* ln_b       = (const float*)d_in[13];
    const float* omics_w    = (const float*)d_in[14];
    const float* omics_b    = (const float*)d_in[15];
    const float* wsi_w      = (const float*)d_in[16];
    const float* wsi_b      = (const float*)d_in[17];
    const float* mlp_w      = (const float*)d_in[18];
    const float* mlp_b      = (const float*)d_in[19];
    const float* wln_g      = (const float*)d_in[20];
    const float* wln_b      = (const float*)d_in[21];
    const float* fuse_w1    = (const float*)d_in[22];
    const float* fuse_b1    = (const float*)d_in[23];
    const float* fuse_w2    = (const float*)d_in[24];
    const float* fuse_b2    = (const float*)d_in[25];
    const float* patches    = (const float*)d_in[26];
    const float* mask       = (const float*)d_in[27];
    const int* src_m2M = (const int*)d_in[28];
    const int* dst_m2M = (const int*)d_in[29];
    const int* src_M2m = (const int*)d_in[30];
    const int* dst_M2m = (const int*)d_in[31];
    const int* src_M2p = (const int*)d_in[32];
    const int* dst_M2p = (const int*)d_in[33];
    const int* src_m2p = (const int*)d_in[34];
    const int* dst_m2p = (const int*)d_in[35];

    float* ws = (float*)d_ws;
    // ---- zeroed region ----
    size_t off = 0;
    float* acc_pat  = ws + off; off += (size_t)BB * HID;       // 4096
    float* pooled   = ws + off; off += (size_t)BB * PD;        // 16384
    float* Wp       = ws + off; off += (size_t)BB * NG;        // [16][22000]
    int* cnt        = (int*)(ws + off); off += NG;             // [22000]
    size_t zero_floats = off;
    // ---- non-zeroed region (16B-aligned: zero_floats % 4 == 0) ----
    unsigned short* agg_bf = (unsigned short*)(ws + off); off += (size_t)NG * HID / 2;
    unsigned short* wb     = (unsigned short*)(ws + off); off += (size_t)2 * HID * HID / 2;
    float* h        = ws + off; off += (size_t)NG * HID;       // [22000][256]
    int* rowptr_A   = (int*)(ws + off); off += NMRNA + 1;
    int* cursor_A   = (int*)(ws + off); off += NMRNA;
    int* rowptr_B   = (int*)(ws + off); off += NMIR + 1;
    int* cursor_B   = (int*)(ws + off); off += NMIR;
    int* srcp_A     = (int*)(ws + off); off += EREG;
    float* wp_A     = ws + off; off += EREG;
    int* srcp_B     = (int*)(ws + off); off += EREG;
    float* wp_B     = ws + off; off += EREG;

    float* out_fused = (float*)d_out;               // [16,4]
    float* out_omics = (float*)d_out + BB * NBINS;  // [16,4]

    hipMemsetAsync(d_ws, 0, zero_floats * sizeof(float), stream);

    // 1. both reg weights -> bf16 (no transpose: [out][in] == MFMA B-fragment layout)
    k_f2b_w<<<(2 * HID * HID + 255) / 256, 256, 0, stream>>>(reg_w_mrna, reg_w_mirna, wb);

    // 2-4. CSR build, both etypes
    k_hist2<<<(2 * EREG + 255) / 256, 256, 0, stream>>>(dst_m2M, dst_M2m, cnt);
    k_scan2<<<2, 1024, 0, stream>>>(cnt, rowptr_A, cursor_A, rowptr_B, cursor_B);
    k_place2<<<(2 * EREG + 255) / 256, 256, 0, stream>>>(
        src_m2M, dst_m2M, w_mir2mrna, cursor_A, srcp_A, wp_A,
        src_M2m, dst_M2m, w_mrna2mir, cursor_B, srcp_B, wp_B);

    // 5. CSR gather (no atomics, no eidx indirection), bf16 agg out
    k_gather2<<<NG, 256, 0, stream>>>(emb_mirna, emb_mrna,
                                      rowptr_A, srcp_A, wp_A,
                                      rowptr_B, srcp_B, wp_B, agg_bf);

    // 6. MFMA node update, both etypes
    k_update2<<<NG / 16, 256, 0, stream>>>(agg_bf, emb_mrna, emb_mirna, wb,
                                           reg_b_mrna, reg_b_mirna, h);

    // 7-8. patient readout: dense weights + skinny matmul
    k_wscatter2<<<(EPM + EPI + 255) / 256, 256, 0, stream>>>(
        src_M2p, dst_M2p, w_mrna2pat, src_m2p, dst_m2p, w_mir2pat, Wp);
    k_pat_dense<<<(NG + GCH - 1) / GCH, 256, 0, stream>>>(Wp, h, acc_pat);

    // 9. wsi masked pooling
    k_pool<<<dim3(PSLICES, BB), 256, 0, stream>>>(patches, mask, pooled);

    // 10. all heads fused: one block per patient
    k_head<<<BB, 256, 0, stream>>>(pooled, mask, acc_pat,
                                   proj_w, proj_b, ln_g, ln_b, omics_w, omics_b,
                                   wsi_w, wsi_b, mlp_w, mlp_b, wln_g, wln_b,
                                   fuse_w1, fuse_b1, fuse_w2, fuse_b2,
                                   out_fused, out_omics);
}